// Round 3
// baseline (524.626 us; speedup 1.0000x reference)
//
#include <hip/hip_runtime.h>
#include <math.h>

// ---------------------------------------------------------------------------
// HGT layer slice. R15: nr_gemm v5 — 64-row blocks + swapped-MFMA LDS stage.
// R14 post-mortem: direct 8B stores doubled store-pipe line transactions
// (16 half-covered lines/instr vs 8 full-line 1KiB instrs) and VGPR=88
// (afrag[2][4]+acc[2][8] live) left no room to pipeline B-loads across
// rels -> latency-bound at 6 waves/CU, 169us (worse than R12's 136).
// Fix: 16 rows/wave (m=1) -> acc=32 VGPR, afrag=16 VGPR; 2x blocks (782x2);
// swapped-MFMA acc (verified R14) staged to wave-private LDS via 8 vector
// ds_write_b64 (vs R12's 64 scalar ds_write_b16), read back 16B/lane,
// 4 x 1KiB fully-contiguous stores per rel. No barriers (wave-private).
//
// attend v2.1 (R9), fp32 score path (R6), parallel scan (R10), [rel][node]
// U/VM layout (R12), qF=VMF[7] alias + U-first dispatch (R14, kept).
// ---------------------------------------------------------------------------

#define N_NODES 50000
#define N_EDGES 500000
#define DIM 128
#define TT 8
#define RR 8
#define RSQRT_DK 0.08838834764831845f

#define CHUNK_GRID 399               // 399*128 = 51072 >= 50000 + 8*127
#define NODE_LIST_LEN (CHUNK_GRID * 128)
#define GRID_E ((N_EDGES + 255) / 256)   // 1954, also covers N
#define GEMM_ROWBLKS ((N_NODES + 63) / 64)    // 782 (64-row blocks)
#define SCAN_BLOCKS ((N_NODES + 255) / 256)   // 196

// word offsets (4B units); _Float16 index = 2*word
#define OFF_U 0                    // UF16 [rel][n][128]
#define OFF_HF 0                   // alias: hF16 [n][128] (dead before U write)
#define OFF_VM 25600000            // VMF16 [rel][n][128]
#define OFF_QF 48000000            // alias: qF16 = VMF[rel=7] slice.
                                   // qF read by U-path blocks (y=0, dispatched
                                   // first, read in prologue); VMF[7] written
                                   // only by y=1 blocks at their LAST rel
                                   // iteration.
#define OFF_KF 51200000
#define OFF_AGGF 54400000
#define OFF_VF 54400000            // alias: vF16 (dead before attend writes agg)
#define OFF_ATTF 57600000          // 65,536 words each, 100k spacing
#define OFF_MSGT 57700000
#define OFF_WVT 57800000
#define OFF_WAT 57900000
#define OFF_INT 58000000           // int region, +701,872 -> 58,701,872 words
#define IO_NLIST 0                 // 51,072
#define IO_CNT_N 51072
#define IO_CUR_N 51080
#define IO_POFF_N 51088
#define IO_DCNT 51104              // 50,000
#define IO_DCUR 101104             // 50,000
#define IO_DOFF 151104             // 50,000
#define IO_DPR 201104              // 500,000 packed (src*8|rel) per CSR slot
#define IO_BLKSUM 701104           // 256 per-scan-block totals
#define IO_BLKOFF 701360           // 256 scanned block offsets; end 701,616

typedef _Float16 half8 __attribute__((ext_vector_type(8)));
typedef _Float16 half4 __attribute__((ext_vector_type(4)));
typedef float f32x4 __attribute__((ext_vector_type(4)));

__global__ void init_kernel(int* wsi) {
    int i = blockIdx.x * blockDim.x + threadIdx.x;
    if (i < NODE_LIST_LEN) wsi[IO_NLIST + i] = -1;
    if (i < 32) wsi[IO_CNT_N + i] = 0;
    if (i < 100000) wsi[IO_DCNT + i] = 0;  // dcnt + dcur contiguous
}

// attF straight [r][d][f]; msgT/WvT/WaT transposed to [.][f][d], all f16
__global__ void convert_kernel(const float* __restrict__ att,
                               const float* __restrict__ msg,
                               const float* __restrict__ Wv,
                               const float* __restrict__ Wa,
                               _Float16* __restrict__ attF,
                               _Float16* __restrict__ msgT,
                               _Float16* __restrict__ WvT,
                               _Float16* __restrict__ WaT) {
    int i = blockIdx.x * 256 + threadIdx.x;
    if (i >= RR * DIM * DIM) return;
    int td = i >> 14, d = (i >> 7) & 127, f = i & 127;
    int tr = (td << 14) + (f << 7) + d;
    attF[i] = (_Float16)att[i];
    msgT[tr] = (_Float16)msg[i];
    WvT[tr] = (_Float16)Wv[i];
    WaT[tr] = (_Float16)Wa[i];
}

__global__ void hconv_kernel(const float* __restrict__ h,
                             _Float16* __restrict__ hF) {
    int i = blockIdx.x * 256 + threadIdx.x;
    if (i < N_NODES * DIM / 4) {
        float4 v = ((const float4*)h)[i];
        half4 o;
        o[0] = (_Float16)v.x; o[1] = (_Float16)v.y;
        o[2] = (_Float16)v.z; o[3] = (_Float16)v.w;
        *(half4*)(hF + (size_t)i * 4) = o;
    }
}

__global__ void hist_kernel(const int* __restrict__ ntype,
                            const int* __restrict__ adj, int* wsi) {
    __shared__ int cn[TT];
    int tid = threadIdx.x;
    if (tid < TT) cn[tid] = 0;
    __syncthreads();
    int i = blockIdx.x * blockDim.x + tid;
    if (i < N_NODES) atomicAdd(&cn[ntype[i]], 1);
    if (i < N_EDGES) atomicAdd(&wsi[IO_DCNT + adj[N_EDGES + i]], 1);
    __syncthreads();
    if (tid < TT && cn[tid] > 0) atomicAdd(&wsi[IO_CNT_N + tid], cn[tid]);
}

__global__ void offsets_kernel(int* wsi) {
    int off = 0;
    for (int t = 0; t < TT; ++t) {
        wsi[IO_POFF_N + t] = off;
        off += ((wsi[IO_CNT_N + t] + 127) >> 7) << 7;  // pad to 128
    }
}

// 3-phase parallel exclusive scan of the 50k dst counts
__global__ __launch_bounds__(256) void scanA_kernel(int* wsi) {
    __shared__ int tmp[256];
    int tid = threadIdx.x;
    int i = blockIdx.x * 256 + tid;
    int v = (i < N_NODES) ? wsi[IO_DCNT + i] : 0;
    tmp[tid] = v;
    __syncthreads();
    for (int off = 1; off < 256; off <<= 1) {
        int t = (tid >= off) ? tmp[tid - off] : 0;
        __syncthreads();
        tmp[tid] += t;
        __syncthreads();
    }
    if (i < N_NODES) wsi[IO_DOFF + i] = tmp[tid] - v;  // block-local exclusive
    if (tid == 255) wsi[IO_BLKSUM + blockIdx.x] = tmp[255];
}

__global__ __launch_bounds__(256) void scanB_kernel(int* wsi) {
    __shared__ int tmp[256];
    int tid = threadIdx.x;
    int v = (tid < SCAN_BLOCKS) ? wsi[IO_BLKSUM + tid] : 0;
    tmp[tid] = v;
    __syncthreads();
    for (int off = 1; off < 256; off <<= 1) {
        int t = (tid >= off) ? tmp[tid - off] : 0;
        __syncthreads();
        tmp[tid] += t;
        __syncthreads();
    }
    wsi[IO_BLKOFF + tid] = tmp[tid] - v;
}

__global__ __launch_bounds__(256) void scanC_kernel(int* wsi) {
    int i = blockIdx.x * 256 + threadIdx.x;
    if (i < N_NODES) wsi[IO_DOFF + i] += wsi[IO_BLKOFF + blockIdx.x];
}

__global__ void scatter_kernel(const int* __restrict__ ntype,
                               const int* __restrict__ etype,
                               const int* __restrict__ adj, int* wsi) {
    __shared__ int cn[TT], bn[TT];
    int tid = threadIdx.x;
    if (tid < TT) cn[tid] = 0;
    __syncthreads();
    int i = blockIdx.x * blockDim.x + tid;
    int t = -1, rnk = 0;
    if (i < N_NODES) {
        t = ntype[i];
        rnk = atomicAdd(&cn[t], 1);
    }
    __syncthreads();
    if (tid < TT && cn[tid] > 0) bn[tid] = atomicAdd(&wsi[IO_CUR_N + tid], cn[tid]);
    __syncthreads();
    if (t >= 0)
        wsi[IO_NLIST + wsi[IO_POFF_N + t] + bn[t] + rnk] = i;
    if (i < N_EDGES) {
        int d = adj[N_EDGES + i];
        int pos = wsi[IO_DOFF + d] + atomicAdd(&wsi[IO_DCUR + d], 1);
        wsi[IO_DPR + pos] = (adj[i] << 3) | etype[i];  // packed src*8|rel
    }
}

// k,q: fp32 vector tile GEMM (score path is argmax-sensitive; R6 post-mortem)
__global__ __launch_bounds__(256) void kq_f32_kernel(
    const float* __restrict__ h, const int* __restrict__ ntype,
    const float* __restrict__ Wk, const float* __restrict__ Wq,
    const int* __restrict__ nlist, _Float16* __restrict__ kout,
    _Float16* __restrict__ qout) {
    __shared__ float hl[32][DIM + 4];
    __shared__ int nid[32];
    int tid = threadIdx.x;
    int base = blockIdx.x * 32;
    if (tid < 32) nid[tid] = nlist[base + tid];
    __syncthreads();
    if (nid[0] < 0) return;
    int t = ntype[nid[0]];

    for (int r2 = 0; r2 < 32; r2 += 2) {
        int row = r2 + (tid >> 7);
        int col = tid & 127;
        int n = nid[row];
        if (n < 0) n = 0;
        hl[row][col] = h[(size_t)n * DIM + col];
    }
    __syncthreads();
    int te = tid >> 5, tc = tid & 31;

#pragma unroll
    for (int w = 0; w < 2; ++w) {
        const float* W = (w == 0 ? Wk : Wq) + (size_t)t * DIM * DIM;
        const float4* W4 = (const float4*)W;
        _Float16* O = (w == 0 ? kout : qout);
        float acc[4][4] = {};
        for (int i = 0; i < DIM; ++i) {
            float4 a = W4[i * 32 + tc];
#pragma unroll
            for (int j = 0; j < 4; ++j) {
                float hv = hl[te * 4 + j][i];
                acc[j][0] += hv * a.x;
                acc[j][1] += hv * a.y;
                acc[j][2] += hv * a.z;
                acc[j][3] += hv * a.w;
            }
        }
#pragma unroll
        for (int j = 0; j < 4; ++j) {
            int n = nid[te * 4 + j];
            if (n >= 0) {
                half4 o;
                o[0] = (_Float16)acc[j][0];
                o[1] = (_Float16)acc[j][1];
                o[2] = (_Float16)acc[j][2];
                o[3] = (_Float16)acc[j][3];
                *(half4*)(O + (size_t)n * DIM + tc * 4) = o;
            }
        }
    }
}

// v: 128-node type-uniform chunk MFMA GEMM (value path: f16-tolerant)
__global__ __launch_bounds__(256) void vproj_kernel(
    const _Float16* __restrict__ hF, const int* __restrict__ ntype,
    const _Float16* __restrict__ WvT, const int* __restrict__ nlist,
    _Float16* __restrict__ vout) {
    __shared__ int nid[128];
    int tid = threadIdx.x;
    if (tid < 128) nid[tid] = nlist[blockIdx.x * 128 + tid];
    __syncthreads();
    if (nid[0] < 0) return;
    int t = ntype[nid[0]];
    int wv = tid >> 6, lane = tid & 63, l16 = lane & 15, quad = lane >> 4;
    int r0 = wv * 32;
    int nA[2];
#pragma unroll
    for (int m = 0; m < 2; ++m) nA[m] = nid[r0 + m * 16 + l16];
    const _Float16* B = WvT + (t << 14);
    f32x4 acc[2][8];
#pragma unroll
    for (int m = 0; m < 2; ++m)
#pragma unroll
        for (int c = 0; c < 8; ++c) acc[m][c] = (f32x4){0.f, 0.f, 0.f, 0.f};
    for (int kk = 0; kk < 4; ++kk) {
        int kb = kk * 32 + quad * 8;
        half8 a[2];
#pragma unroll
        for (int m = 0; m < 2; ++m)
            a[m] = (nA[m] >= 0)
                       ? *(const half8*)(hF + (size_t)nA[m] * DIM + kb)
                       : (half8){0, 0, 0, 0, 0, 0, 0, 0};
#pragma unroll
        for (int c = 0; c < 8; ++c) {
            half8 b = *(const half8*)(B + (c * 16 + l16) * DIM + kb);
#pragma unroll
            for (int m = 0; m < 2; ++m)
                acc[m][c] = __builtin_amdgcn_mfma_f32_16x16x32_f16(
                    a[m], b, acc[m][c], 0, 0, 0);
        }
    }
#pragma unroll
    for (int m = 0; m < 2; ++m)
#pragma unroll
        for (int c = 0; c < 8; ++c)
#pragma unroll
            for (int rg = 0; rg < 4; ++rg) {
                int node = nid[r0 + m * 16 + quad * 4 + rg];
                if (node >= 0)
                    vout[(size_t)node * DIM + c * 16 + l16] =
                        (_Float16)acc[m][c][rg];
            }
}

// ---------------------------------------------------------------------------
// nr_gemm v5: Out[rel][n][:] = scale_r * A[n,:] @ B[rel]^T for all 8 rels.
// blockIdx.y: 0 = U (A=qF, B=attF), 1 = VM (A=vF, B=msgT); y slower than x
// -> all qF readers dispatch before any VMF writer (qF aliases VMF[7],
// clobbered only at the LAST rel iteration of y=1 blocks).
// 64 rows/block, 16 rows/wave (m=1): acc=32 VGPR, afrag=16 VGPR -> room to
// pipeline B-loads; 1564 blocks (~6/CU) for TLP.
// Swapped MFMA (R14-verified): acc[c][rg] = Out[node=row0w+l16]
// [feat=c*16+quad*4+rg]. Epilogue: 8 vector ds_write_b64 to wave-private
// stage -> 4 ds_read_b128 -> 4 x 1KiB fully-contiguous global stores/rel.
// No barriers (same-wave LDS, lgkmcnt orders it; R12-proven pattern).
// ---------------------------------------------------------------------------
__global__ __launch_bounds__(256) void nr_gemm2_kernel(
    const _Float16* __restrict__ qF, const _Float16* __restrict__ attF,
    _Float16* __restrict__ UF, const _Float16* __restrict__ vF,
    const _Float16* __restrict__ msgT, _Float16* __restrict__ VMF,
    const float* __restrict__ pri) {
    __shared__ _Float16 stage[4][16][136];
    int which = blockIdx.y;
    const _Float16* A = which ? vF : qF;
    const _Float16* B = which ? msgT : attF;
    _Float16* Of = which ? VMF : UF;
    int tid = threadIdx.x;
    int wv = tid >> 6, lane = tid & 63;
    int l16 = lane & 15, quad = lane >> 4;
    int row0 = blockIdx.x * 64 + wv * 16;   // this wave's 16 rows

    // A fragments once: afrag[kk] covers row row0+l16, k=kk*32+quad*8
    int nodeA = row0 + l16;
    half8 afrag[4];
#pragma unroll
    for (int kk = 0; kk < 4; ++kk)
        afrag[kk] =
            (nodeA < N_NODES)
                ? *(const half8*)(A + (size_t)nodeA * DIM + kk * 32 + quad * 8)
                : (half8){0, 0, 0, 0, 0, 0, 0, 0};

    for (int rel = 0; rel < RR; ++rel) {
        float scale = which ? 1.0f : pri[rel] * RSQRT_DK;
        const _Float16* Bb = B + (rel << 14);
        f32x4 acc[8];
#pragma unroll
        for (int c = 0; c < 8; ++c) acc[c] = (f32x4){0.f, 0.f, 0.f, 0.f};
        for (int kk = 0; kk < 4; ++kk) {
            int kb = kk * 32 + quad * 8;
#pragma unroll
            for (int c = 0; c < 8; ++c) {
                half8 b = *(const half8*)(Bb + (c * 16 + l16) * DIM + kb);
                acc[c] = __builtin_amdgcn_mfma_f32_16x16x32_f16(
                    b, afrag[kk], acc[c], 0, 0, 0);
            }
        }
        // stage transposed acc into wave-private LDS: row = local node l16,
        // feature = c*16 + quad*4 + rg  (8B vector writes, ~2-way = free)
#pragma unroll
        for (int c = 0; c < 8; ++c) {
            half4 o;
#pragma unroll
            for (int rg = 0; rg < 4; ++rg)
                o[rg] = (_Float16)(acc[c][rg] * scale);
            *(half4*)&stage[wv][l16][c * 16 + quad * 4] = o;
        }
        // read back row-wise and store: 4 iterations x (4 rows x 256B) = 1KiB
        // contiguous per instruction
        _Float16* Orel = Of + ((size_t)rel * N_NODES + row0) * DIM;
#pragma unroll
        for (int it = 0; it < 4; ++it) {
            int row = it * 4 + quad;
            if (row0 + row < N_NODES) {
                half8 v = *(const half8*)&stage[wv][row][l16 * 8];
                *(half8*)(Orel + (size_t)row * DIM + l16 * 8) = v;
            }
        }
    }
}

// ---------------------------------------------------------------------------
// attend v2.1 (R9-proven); U/VM indexed [rel][node][128] (R12 relayout).
// ---------------------------------------------------------------------------
__global__ __launch_bounds__(256) void attend_kernel(
    const _Float16* __restrict__ kF, const _Float16* __restrict__ UF,
    const _Float16* __restrict__ VMF, const int* __restrict__ dpr,
    const int* __restrict__ doff, const int* __restrict__ dcnt,
    _Float16* __restrict__ aggF) {
    int wv = threadIdx.x >> 6, lane = threadIdx.x & 63;
    int dst = blockIdx.x * 4 + wv;
    if (dst >= N_NODES) return;
    int l16 = lane & 15, g = lane >> 4, l8 = lane & 7;
    int beg = doff[dst], cnt = dcnt[dst];

    float m_own = -3e38f, sum_own = 0.f;
    float s0 = 0.f, s1 = 0.f, s2 = 0.f;
    int p0 = 0, p1 = 0, p2 = 0;

    // phase 1: scores, park (s, pr), lane-owned per-rel max
    for (int j0 = 0; j0 < cnt; j0 += 4) {
        int j = j0 + g;
        bool valid = j < cnt;
        int pr = valid ? dpr[beg + j] : 0;
        int src = pr >> 3, rel = pr & 7;
        half8 kv = *(const half8*)(kF + (size_t)src * DIM + l16 * 8);
        half8 uv = *(const half8*)(UF + ((size_t)rel * N_NODES + dst) * DIM +
                                   l16 * 8);
        float s = 0.f;
#pragma unroll
        for (int i = 0; i < 8; ++i) s += (float)kv[i] * (float)uv[i];
        s += __shfl_xor(s, 1, 16);
        s += __shfl_xor(s, 2, 16);
        s += __shfl_xor(s, 4, 16);
        s += __shfl_xor(s, 8, 16);
        if (!valid) s = -3e38f;
        int slot = j0 >> 6;            // wave-uniform
        int idx = (j0 >> 2) & 15;      // wave-uniform
        if (l16 == idx) {
            if (slot == 0) { s0 = s; p0 = pr; }
            else if (slot == 1) { s1 = s; p1 = pr; }
            else if (slot == 2) { s2 = s; p2 = pr; }
        }
        if (valid && l8 == rel && s > m_own) m_own = s;
    }
    // merge per-rel max across the 4 groups
    m_own = fmaxf(m_own, __shfl_xor(m_own, 16, 64));
    m_own = fmaxf(m_own, __shfl_xor(m_own, 32, 64));

    // phase 2: ex = valid ? exp(s - m[rel]) : 0; park ex; lane-owned sum
    for (int j0 = 0; j0 < cnt; j0 += 4) {
        int j = j0 + g;
        bool valid = j < cnt;
        int slot = j0 >> 6;
        int idx = (j0 >> 2) & 15;
        float s;
        int pr;
        if (slot < 3) {
            float sv = (slot == 0) ? s0 : (slot == 1) ? s1 : s2;
            int pv = (slot == 0) ? p0 : (slot == 1) ? p1 : p2;
            s = __shfl(sv, idx, 16);
            pr = __shfl(pv, idx, 16);
        } else {  // overflow fallback: recompute (cnt>192 ~ never at deg~10)
            pr = valid ? dpr[beg + j] : 0;
            int src = pr >> 3, rel = pr & 7;
            half8 kv = *(const half8*)(kF + (size_t)src * DIM + l16 * 8);
            half8 uv = *(const half8*)(UF +
                                       ((size_t)rel * N_NODES + dst) * DIM +
                                       l16 * 8);
            s = 0.f;
#pragma unroll
            for (int i = 0; i < 8; ++i) s += (float)kv[i] * (float)uv[i];
            s += __shfl_xor(s, 1, 16);
            s += __shfl_xor(s, 2, 16);
            s += __shfl_xor(s, 4, 16);
            s += __shfl_xor(s, 8, 16);
        }
        int rel = pr & 7;
        float mr = __shfl(m_own, rel, 8);
        float ex = valid ? __expf(s - mr) : 0.f;  // mask padding edges
        if (l16 == idx) {
            if (slot == 0) s0 = ex;
            else if (slot == 1) s1 = ex;
            else if (slot == 2) s2 = ex;
        }
        if (l8 == rel) sum_own += ex;
    }
    // merge per-rel sums; invert once
    sum_own += __shfl_xor(sum_own, 16, 64);
    sum_own += __shfl_xor(sum_own, 32, 64);
    float inv_own = (sum_own > 0.f) ? 1.f / sum_own : 0.f;

    // phase 3: acc += alpha * VM[rel][src]  (parked ex is already 0 for pads)
    float acc[8] = {0.f, 0.f, 0.f, 0.f, 0.f, 0.f, 0.f, 0.f};
    for (int j0 = 0; j0 < cnt; j0 += 4) {
        int j = j0 + g;
        bool valid = j < cnt;
        int slot = j0 >> 6;
        int idx = (j0 >> 2) & 15;
        float ex;
        int pr;
        if (slot < 3) {
            float sv = (slot == 0) ? s0 : (slot == 1) ? s1 : s2;
            int pv = (slot == 0) ? p0 : (slot == 1) ? p1 : p2;
            ex = __shfl(sv, idx, 16);
            pr = __shfl(pv, idx, 16);
        } else {
            pr = valid ? dpr[beg + j] : 0;
            int src = pr >> 3, rel = pr & 7;
            half8 kv = *(const half8*)(kF + (size_t)src * DIM + l16 * 8);
            half8 uv = *(const half8*)(UF +
                                       ((size_t)rel * N_NODES + dst) * DIM +
                                       l16 * 8);
            float s = 0.f;
#pragma unroll
            for (int i = 0; i < 8; ++i) s += (float)kv[i] * (float)uv[i];
            s += __shfl_xor(s, 1, 16);
            s += __shfl_xor(s, 2, 16);
            s += __shfl_xor(s, 4, 16);
            s += __shfl_xor(s, 8, 16);
            float mr = __shfl(m_own, (pr & 7), 8);
            ex = valid ? __expf(s - mr) : 0.f;
        }
        int rel = pr & 7, src = pr >> 3;
        float alpha = ex * __shfl(inv_own, rel, 8);
        half8 v = *(const half8*)(VMF + ((size_t)rel * N_NODES + src) * DIM +
                                  l16 * 8);
#pragma unroll
        for (int i = 0; i < 8; ++i) acc[i] += alpha * (float)v[i];
    }
    // merge acc across the 4 groups (each covers the full 128 dims)
#pragma unroll
    for (int i = 0; i < 8; ++i) {
        acc[i] += __shfl_xor(acc[i], 16, 64);
        acc[i] += __shfl_xor(acc[i], 32, 64);
    }
    if (g == 0) {
        half8 o;
#pragma unroll
        for (int i = 0; i < 8; ++i) o[i] = (_Float16)acc[i];
        *(half8*)(aggF + (size_t)dst * DIM + l16 * 8) = o;
    }
}

// out: 128-node type-uniform chunk MFMA GEMM, fp32 stores with sigmoid gate
__global__ __launch_bounds__(256) void out_kernel(
    const _Float16* __restrict__ aggF, const int* __restrict__ ntype,
    const _Float16* __restrict__ WaT, const float* __restrict__ skip,
    const int* __restrict__ nlist, float* __restrict__ out) {
    __shared__ int nid[128];
    int tid = threadIdx.x;
    if (tid < 128) nid[tid] = nlist[blockIdx.x * 128 + tid];
    __syncthreads();
    if (nid[0] < 0) return;
    int t = ntype[nid[0]];
    float sig = 1.f / (1.f + __expf(-skip[t]));
    int wv = tid >> 6, lane = tid & 63, l16 = lane & 15, quad = lane >> 4;
    int r0 = wv * 32;
    int nA[2];
#pragma unroll
    for (int m = 0; m < 2; ++m) nA[m] = nid[r0 + m * 16 + l16];
    const _Float16* B = WaT + (t << 14);
    f32x4 acc[2][8];
#pragma unroll
    for (int m = 0; m < 2; ++m)
#pragma unroll
        for (int c = 0; c < 8; ++c) acc[m][c] = (f32x4){0.f, 0.f, 0.f, 0.f};
    for (int kk = 0; kk < 4; ++kk) {
        int kb = kk * 32 + quad * 8;
        half8 a[2];
#pragma unroll
        for (int m = 0; m < 2; ++m)
            a[m] = (nA[m] >= 0)
                       ? *(const half8*)(aggF + (size_t)nA[m] * DIM + kb)
                       : (half8){0, 0, 0, 0, 0, 0, 0, 0};
#pragma unroll
        for (int c = 0; c < 8; ++c) {
            half8 b = *(const half8*)(B + (c * 16 + l16) * DIM + kb);
#pragma unroll
            for (int m = 0; m < 2; ++m)
                acc[m][c] = __builtin_amdgcn_mfma_f32_16x16x32_f16(
                    a[m], b, acc[m][c], 0, 0, 0);
        }
    }
#pragma unroll
    for (int m = 0; m < 2; ++m)
#pragma unroll
        for (int c = 0; c < 8; ++c)
#pragma unroll
            for (int rg = 0; rg < 4; ++rg) {
                int node = nid[r0 + m * 16 + quad * 4 + rg];
                if (node >= 0)
                    out[(size_t)node * DIM + c * 16 + l16] =
                        acc[m][c][rg] * sig;
            }
}

extern "C" void kernel_launch(void* const* d_in, const int* in_sizes, int n_in,
                              void* d_out, int out_size, void* d_ws,
                              size_t ws_size, hipStream_t stream) {
    const float* h = (const float*)d_in[0];
    const int* adj = (const int*)d_in[1];
    const int* etype = (const int*)d_in[2];
    const int* ntype = (const int*)d_in[3];
    const float* Wk = (const float*)d_in[6];
    const float* Wq = (const float*)d_in[7];
    const float* Wv = (const float*)d_in[8];
    const float* Wa = (const float*)d_in[9];
    const float* pri = (const float*)d_in[10];
    const float* att = (const float*)d_in[11];
    const float* msg = (const float*)d_in[12];
    const float* skip = (const float*)d_in[13];
    float* out = (float*)d_out;

    int* wsi = (int*)d_ws + OFF_INT;
    _Float16* wsh = (_Float16*)d_ws;
    _Float16* UF = wsh + (size_t)OFF_U * 2;
    _Float16* hF = wsh + (size_t)OFF_HF * 2;
    _Float16* VMF = wsh + (size_t)OFF_VM * 2;
    _Float16* qF = wsh + (size_t)OFF_QF * 2;
    _Float16* kF = wsh + (size_t)OFF_KF * 2;
    _Float16* aggF = wsh + (size_t)OFF_AGGF * 2;
    _Float16* vF = wsh + (size_t)OFF_VF * 2;
    _Float16* attF = wsh + (size_t)OFF_ATTF * 2;
    _Float16* msgT = wsh + (size_t)OFF_MSGT * 2;
    _Float16* WvT = wsh + (size_t)OFF_WVT * 2;
    _Float16* WaT = wsh + (size_t)OFF_WAT * 2;

    init_kernel<<<(100000 + 255) / 256, 256, 0, stream>>>(wsi);
    convert_kernel<<<(RR * DIM * DIM + 255) / 256, 256, 0, stream>>>(
        att, msg, Wv, Wa, attF, msgT, WvT, WaT);
    hconv_kernel<<<(N_NODES * DIM / 4 + 255) / 256, 256, 0, stream>>>(h, hF);
    hist_kernel<<<GRID_E, 256, 0, stream>>>(ntype, adj, wsi);
    offsets_kernel<<<1, 1, 0, stream>>>(wsi);
    scanA_kernel<<<SCAN_BLOCKS, 256, 0, stream>>>(wsi);
    scanB_kernel<<<1, 256, 0, stream>>>(wsi);
    scanC_kernel<<<SCAN_BLOCKS, 256, 0, stream>>>(wsi);
    scatter_kernel<<<GRID_E, 256, 0, stream>>>(ntype, etype, adj, wsi);
    kq_f32_kernel<<<CHUNK_GRID * 4, 256, 0, stream>>>(h, ntype, Wk, Wq,
                                                      wsi + IO_NLIST, kF, qF);
    vproj_kernel<<<CHUNK_GRID, 256, 0, stream>>>(hF, ntype, WvT,
                                                 wsi + IO_NLIST, vF);
    {
        dim3 g(GEMM_ROWBLKS, 2);  // y = which (slowest): all U blocks first
        nr_gemm2_kernel<<<g, 256, 0, stream>>>(qF, attF, UF, vF, msgT, VMF,
                                               pri);
    }
    attend_kernel<<<(N_NODES + 3) / 4, 256, 0, stream>>>(
        kF, UF, VMF, wsi + IO_DPR, wsi + IO_DOFF, wsi + IO_DCNT, aggF);
    out_kernel<<<CHUNK_GRID, 256, 0, stream>>>(aggF, ntype, WaT, skip,
                                               wsi + IO_NLIST, out);
}

// Round 4
// 396.312 us; speedup vs baseline: 1.3238x; 1.3238x over previous
//
#include <hip/hip_runtime.h>
#include <math.h>

// ---------------------------------------------------------------------------
// HGT layer slice. R16: nr_gemm v6 — inverted loop nest, register-resident B.
// R15 post-mortem: all nr_gemm variants re-loaded the FULL 32KB B matrix
// from L2 per wave per rel (R15: 1.6 GB of L2 traffic; B==L1 size so L1
// thrashes; every rel iteration serialized on ~300cy L2 latency). That —
// not occupancy, not the epilogue — was the bottleneck (R14/R15 regressed
// while "fixing" the epilogue/occupancy).
// Fix: block = one (path, rel); B loaded ONCE into 128 VGPRs; stream 7x64-row
// node tiles with double-buffered A-frag prefetch. B traffic 1.6GB -> 100MB
// one-time. Two launches (U then VM): stream order makes qF=VMF[7] alias
// provably safe (R13 race class eliminated). 1-D grid with chunk=bid%112:
// 112==0 mod 8 -> all 8 rels of a chunk on the same XCD -> chunk's A rows
// L2-resident across rels (HBM A-read ~once).
// Epilogue unchanged from R15 (swapped-MFMA acc -> wave-private LDS
// transpose -> 4x1KiB contiguous stores; verified R14/R15).
//
// attend v2.1 (R9), fp32 score path (R6), parallel scan (R10), [rel][node]
// U/VM layout (R12), qF=VMF[7] alias (R14).
// ---------------------------------------------------------------------------

#define N_NODES 50000
#define N_EDGES 500000
#define DIM 128
#define TT 8
#define RR 8
#define RSQRT_DK 0.08838834764831845f

#define CHUNK_GRID 399               // 399*128 = 51072 >= 50000 + 8*127
#define NODE_LIST_LEN (CHUNK_GRID * 128)
#define GRID_E ((N_EDGES + 255) / 256)   // 1954, also covers N
#define SCAN_BLOCKS ((N_NODES + 255) / 256)   // 196

// nr_gemm v6 geometry: 112 chunks x 448 rows (7 iters x 64) = 50176 >= 50000
// 112 % 8 == 0 -> blocks rel*112+c land on xcd = c%8 for every rel.
#define NR3_CHUNKS 112
#define NR3_ROWS 448
#define NR3_ITERS 7

// word offsets (4B units); _Float16 index = 2*word
#define OFF_U 0                    // UF16 [rel][n][128]
#define OFF_HF 0                   // alias: hF16 [n][128] (dead before U write)
#define OFF_VM 25600000            // VMF16 [rel][n][128]
#define OFF_QF 48000000            // alias: qF16 = VMF[rel=7] slice.
                                   // SAFE: U launch (reads qF) completes
                                   // before VM launch (writes VMF) starts —
                                   // separate kernels, stream-ordered.
#define OFF_KF 51200000
#define OFF_AGGF 54400000
#define OFF_VF 54400000            // alias: vF16 (dead before attend writes agg)
#define OFF_ATTF 57600000          // 65,536 words each, 100k spacing
#define OFF_MSGT 57700000
#define OFF_WVT 57800000
#define OFF_WAT 57900000
#define OFF_INT 58000000           // int region, +701,872 -> 58,701,872 words
#define IO_NLIST 0                 // 51,072
#define IO_CNT_N 51072
#define IO_CUR_N 51080
#define IO_POFF_N 51088
#define IO_DCNT 51104              // 50,000
#define IO_DCUR 101104             // 50,000
#define IO_DOFF 151104             // 50,000
#define IO_DPR 201104              // 500,000 packed (src*8|rel) per CSR slot
#define IO_BLKSUM 701104           // 256 per-scan-block totals
#define IO_BLKOFF 701360           // 256 scanned block offsets; end 701,616

typedef _Float16 half8 __attribute__((ext_vector_type(8)));
typedef _Float16 half4 __attribute__((ext_vector_type(4)));
typedef float f32x4 __attribute__((ext_vector_type(4)));

__global__ void init_kernel(int* wsi) {
    int i = blockIdx.x * blockDim.x + threadIdx.x;
    if (i < NODE_LIST_LEN) wsi[IO_NLIST + i] = -1;
    if (i < 32) wsi[IO_CNT_N + i] = 0;
    if (i < 100000) wsi[IO_DCNT + i] = 0;  // dcnt + dcur contiguous
}

// attF straight [r][d][f]; msgT/WvT/WaT transposed to [.][f][d], all f16
__global__ void convert_kernel(const float* __restrict__ att,
                               const float* __restrict__ msg,
                               const float* __restrict__ Wv,
                               const float* __restrict__ Wa,
                               _Float16* __restrict__ attF,
                               _Float16* __restrict__ msgT,
                               _Float16* __restrict__ WvT,
                               _Float16* __restrict__ WaT) {
    int i = blockIdx.x * 256 + threadIdx.x;
    if (i >= RR * DIM * DIM) return;
    int td = i >> 14, d = (i >> 7) & 127, f = i & 127;
    int tr = (td << 14) + (f << 7) + d;
    attF[i] = (_Float16)att[i];
    msgT[tr] = (_Float16)msg[i];
    WvT[tr] = (_Float16)Wv[i];
    WaT[tr] = (_Float16)Wa[i];
}

__global__ void hconv_kernel(const float* __restrict__ h,
                             _Float16* __restrict__ hF) {
    int i = blockIdx.x * 256 + threadIdx.x;
    if (i < N_NODES * DIM / 4) {
        float4 v = ((const float4*)h)[i];
        half4 o;
        o[0] = (_Float16)v.x; o[1] = (_Float16)v.y;
        o[2] = (_Float16)v.z; o[3] = (_Float16)v.w;
        *(half4*)(hF + (size_t)i * 4) = o;
    }
}

__global__ void hist_kernel(const int* __restrict__ ntype,
                            const int* __restrict__ adj, int* wsi) {
    __shared__ int cn[TT];
    int tid = threadIdx.x;
    if (tid < TT) cn[tid] = 0;
    __syncthreads();
    int i = blockIdx.x * blockDim.x + tid;
    if (i < N_NODES) atomicAdd(&cn[ntype[i]], 1);
    if (i < N_EDGES) atomicAdd(&wsi[IO_DCNT + adj[N_EDGES + i]], 1);
    __syncthreads();
    if (tid < TT && cn[tid] > 0) atomicAdd(&wsi[IO_CNT_N + tid], cn[tid]);
}

__global__ void offsets_kernel(int* wsi) {
    int off = 0;
    for (int t = 0; t < TT; ++t) {
        wsi[IO_POFF_N + t] = off;
        off += ((wsi[IO_CNT_N + t] + 127) >> 7) << 7;  // pad to 128
    }
}

// 3-phase parallel exclusive scan of the 50k dst counts
__global__ __launch_bounds__(256) void scanA_kernel(int* wsi) {
    __shared__ int tmp[256];
    int tid = threadIdx.x;
    int i = blockIdx.x * 256 + tid;
    int v = (i < N_NODES) ? wsi[IO_DCNT + i] : 0;
    tmp[tid] = v;
    __syncthreads();
    for (int off = 1; off < 256; off <<= 1) {
        int t = (tid >= off) ? tmp[tid - off] : 0;
        __syncthreads();
        tmp[tid] += t;
        __syncthreads();
    }
    if (i < N_NODES) wsi[IO_DOFF + i] = tmp[tid] - v;  // block-local exclusive
    if (tid == 255) wsi[IO_BLKSUM + blockIdx.x] = tmp[255];
}

__global__ __launch_bounds__(256) void scanB_kernel(int* wsi) {
    __shared__ int tmp[256];
    int tid = threadIdx.x;
    int v = (tid < SCAN_BLOCKS) ? wsi[IO_BLKSUM + tid] : 0;
    tmp[tid] = v;
    __syncthreads();
    for (int off = 1; off < 256; off <<= 1) {
        int t = (tid >= off) ? tmp[tid - off] : 0;
        __syncthreads();
        tmp[tid] += t;
        __syncthreads();
    }
    wsi[IO_BLKOFF + tid] = tmp[tid] - v;
}

__global__ __launch_bounds__(256) void scanC_kernel(int* wsi) {
    int i = blockIdx.x * 256 + threadIdx.x;
    if (i < N_NODES) wsi[IO_DOFF + i] += wsi[IO_BLKOFF + blockIdx.x];
}

__global__ void scatter_kernel(const int* __restrict__ ntype,
                               const int* __restrict__ etype,
                               const int* __restrict__ adj, int* wsi) {
    __shared__ int cn[TT], bn[TT];
    int tid = threadIdx.x;
    if (tid < TT) cn[tid] = 0;
    __syncthreads();
    int i = blockIdx.x * blockDim.x + tid;
    int t = -1, rnk = 0;
    if (i < N_NODES) {
        t = ntype[i];
        rnk = atomicAdd(&cn[t], 1);
    }
    __syncthreads();
    if (tid < TT && cn[tid] > 0) bn[tid] = atomicAdd(&wsi[IO_CUR_N + tid], cn[tid]);
    __syncthreads();
    if (t >= 0)
        wsi[IO_NLIST + wsi[IO_POFF_N + t] + bn[t] + rnk] = i;
    if (i < N_EDGES) {
        int d = adj[N_EDGES + i];
        int pos = wsi[IO_DOFF + d] + atomicAdd(&wsi[IO_DCUR + d], 1);
        wsi[IO_DPR + pos] = (adj[i] << 3) | etype[i];  // packed src*8|rel
    }
}

// k,q: fp32 vector tile GEMM (score path is argmax-sensitive; R6 post-mortem)
__global__ __launch_bounds__(256) void kq_f32_kernel(
    const float* __restrict__ h, const int* __restrict__ ntype,
    const float* __restrict__ Wk, const float* __restrict__ Wq,
    const int* __restrict__ nlist, _Float16* __restrict__ kout,
    _Float16* __restrict__ qout) {
    __shared__ float hl[32][DIM + 4];
    __shared__ int nid[32];
    int tid = threadIdx.x;
    int base = blockIdx.x * 32;
    if (tid < 32) nid[tid] = nlist[base + tid];
    __syncthreads();
    if (nid[0] < 0) return;
    int t = ntype[nid[0]];

    for (int r2 = 0; r2 < 32; r2 += 2) {
        int row = r2 + (tid >> 7);
        int col = tid & 127;
        int n = nid[row];
        if (n < 0) n = 0;
        hl[row][col] = h[(size_t)n * DIM + col];
    }
    __syncthreads();
    int te = tid >> 5, tc = tid & 31;

#pragma unroll
    for (int w = 0; w < 2; ++w) {
        const float* W = (w == 0 ? Wk : Wq) + (size_t)t * DIM * DIM;
        const float4* W4 = (const float4*)W;
        _Float16* O = (w == 0 ? kout : qout);
        float acc[4][4] = {};
        for (int i = 0; i < DIM; ++i) {
            float4 a = W4[i * 32 + tc];
#pragma unroll
            for (int j = 0; j < 4; ++j) {
                float hv = hl[te * 4 + j][i];
                acc[j][0] += hv * a.x;
                acc[j][1] += hv * a.y;
                acc[j][2] += hv * a.z;
                acc[j][3] += hv * a.w;
            }
        }
#pragma unroll
        for (int j = 0; j < 4; ++j) {
            int n = nid[te * 4 + j];
            if (n >= 0) {
                half4 o;
                o[0] = (_Float16)acc[j][0];
                o[1] = (_Float16)acc[j][1];
                o[2] = (_Float16)acc[j][2];
                o[3] = (_Float16)acc[j][3];
                *(half4*)(O + (size_t)n * DIM + tc * 4) = o;
            }
        }
    }
}

// v: 128-node type-uniform chunk MFMA GEMM (value path: f16-tolerant)
__global__ __launch_bounds__(256) void vproj_kernel(
    const _Float16* __restrict__ hF, const int* __restrict__ ntype,
    const _Float16* __restrict__ WvT, const int* __restrict__ nlist,
    _Float16* __restrict__ vout) {
    __shared__ int nid[128];
    int tid = threadIdx.x;
    if (tid < 128) nid[tid] = nlist[blockIdx.x * 128 + tid];
    __syncthreads();
    if (nid[0] < 0) return;
    int t = ntype[nid[0]];
    int wv = tid >> 6, lane = tid & 63, l16 = lane & 15, quad = lane >> 4;
    int r0 = wv * 32;
    int nA[2];
#pragma unroll
    for (int m = 0; m < 2; ++m) nA[m] = nid[r0 + m * 16 + l16];
    const _Float16* B = WvT + (t << 14);
    f32x4 acc[2][8];
#pragma unroll
    for (int m = 0; m < 2; ++m)
#pragma unroll
        for (int c = 0; c < 8; ++c) acc[m][c] = (f32x4){0.f, 0.f, 0.f, 0.f};
    for (int kk = 0; kk < 4; ++kk) {
        int kb = kk * 32 + quad * 8;
        half8 a[2];
#pragma unroll
        for (int m = 0; m < 2; ++m)
            a[m] = (nA[m] >= 0)
                       ? *(const half8*)(hF + (size_t)nA[m] * DIM + kb)
                       : (half8){0, 0, 0, 0, 0, 0, 0, 0};
#pragma unroll
        for (int c = 0; c < 8; ++c) {
            half8 b = *(const half8*)(B + (c * 16 + l16) * DIM + kb);
#pragma unroll
            for (int m = 0; m < 2; ++m)
                acc[m][c] = __builtin_amdgcn_mfma_f32_16x16x32_f16(
                    a[m], b, acc[m][c], 0, 0, 0);
        }
    }
#pragma unroll
    for (int m = 0; m < 2; ++m)
#pragma unroll
        for (int c = 0; c < 8; ++c)
#pragma unroll
            for (int rg = 0; rg < 4; ++rg) {
                int node = nid[r0 + m * 16 + quad * 4 + rg];
                if (node >= 0)
                    vout[(size_t)node * DIM + c * 16 + l16] =
                        (_Float16)acc[m][c][rg];
            }
}

// ---------------------------------------------------------------------------
// nr_gemm v6: one block = one rel; B register-resident (128 VGPR); stream
// NR3_ITERS x 64-row tiles with double-buffered A prefetch.
// bid = rel*NR3_CHUNKS + chunk; NR3_CHUNKS%8==0 -> xcd = chunk%8 for all
// rels -> a chunk's A rows are fetched once per XCD-L2 and served 8x.
// Swapped MFMA (R14/R15-verified): acc[c][rg] = Out[node=row0+l16]
// [feat=c*16+quad*4+rg]. Epilogue: 8 ds_write_b64 -> 4 ds_read_b128 ->
// 4 x 1KiB contiguous stores per tile. Wave-private LDS, no barriers.
// ---------------------------------------------------------------------------
__global__ __launch_bounds__(256, 2) void nr_gemm3_kernel(
    const _Float16* __restrict__ A, const _Float16* __restrict__ B8,
    _Float16* __restrict__ Out, const float* __restrict__ pri, int isU) {
    __shared__ _Float16 stage[4][16][136];
    int bid = blockIdx.x;
    int rel = bid / NR3_CHUNKS;
    int chunk = bid - rel * NR3_CHUNKS;
    float scale = isU ? pri[rel] * RSQRT_DK : 1.0f;
    const _Float16* Bb = B8 + (rel << 14);
    int tid = threadIdx.x;
    int wv = tid >> 6, lane = tid & 63;
    int l16 = lane & 15, quad = lane >> 4;

    // B fragments once: bfrag[c][kk] covers B-row c*16+l16, k=kk*32+quad*8
    half8 bfrag[8][4];
#pragma unroll
    for (int c = 0; c < 8; ++c)
#pragma unroll
        for (int kk = 0; kk < 4; ++kk)
            bfrag[c][kk] =
                *(const half8*)(Bb + (c * 16 + l16) * DIM + kk * 32 + quad * 8);

    _Float16* Orel = Out + (size_t)rel * N_NODES * DIM;
    int base = chunk * NR3_ROWS + wv * 16;  // this wave's first tile row

    // prefetch tile 0
    half8 aNow[4], aNext[4];
    {
        int nodeA = base + l16;
#pragma unroll
        for (int kk = 0; kk < 4; ++kk)
            aNow[kk] = (nodeA < N_NODES)
                           ? *(const half8*)(A + (size_t)nodeA * DIM +
                                             kk * 32 + quad * 8)
                           : (half8){0, 0, 0, 0, 0, 0, 0, 0};
    }

    for (int it = 0; it < NR3_ITERS; ++it) {
        int row0 = base + it * 64;
        // prefetch next tile's A while this tile computes
        if (it + 1 < NR3_ITERS) {
            int nodeA = row0 + 64 + l16;
#pragma unroll
            for (int kk = 0; kk < 4; ++kk)
                aNext[kk] = (nodeA < N_NODES)
                                ? *(const half8*)(A + (size_t)nodeA * DIM +
                                                  kk * 32 + quad * 8)
                                : (half8){0, 0, 0, 0, 0, 0, 0, 0};
        }
        f32x4 acc[8];
#pragma unroll
        for (int c = 0; c < 8; ++c) acc[c] = (f32x4){0.f, 0.f, 0.f, 0.f};
#pragma unroll
        for (int kk = 0; kk < 4; ++kk)
#pragma unroll
            for (int c = 0; c < 8; ++c)
                acc[c] = __builtin_amdgcn_mfma_f32_16x16x32_f16(
                    bfrag[c][kk], aNow[kk], acc[c], 0, 0, 0);
        // stage transposed acc into wave-private LDS: row = local node l16,
        // feature = c*16 + quad*4 + rg
#pragma unroll
        for (int c = 0; c < 8; ++c) {
            half4 o;
#pragma unroll
            for (int rg = 0; rg < 4; ++rg)
                o[rg] = (_Float16)(acc[c][rg] * scale);
            *(half4*)&stage[wv][l16][c * 16 + quad * 4] = o;
        }
        // read back row-wise: 4 x (4 rows x 256B) = 1KiB contiguous stores
        _Float16* Op = Orel + (size_t)row0 * DIM;
#pragma unroll
        for (int s = 0; s < 4; ++s) {
            int row = s * 4 + quad;
            if (row0 + row < N_NODES) {
                half8 v = *(const half8*)&stage[wv][row][l16 * 8];
                *(half8*)(Op + (size_t)row * DIM + l16 * 8) = v;
            }
        }
#pragma unroll
        for (int kk = 0; kk < 4; ++kk) aNow[kk] = aNext[kk];
    }
}

// ---------------------------------------------------------------------------
// attend v2.1 (R9-proven); U/VM indexed [rel][node][128] (R12 relayout).
// ---------------------------------------------------------------------------
__global__ __launch_bounds__(256) void attend_kernel(
    const _Float16* __restrict__ kF, const _Float16* __restrict__ UF,
    const _Float16* __restrict__ VMF, const int* __restrict__ dpr,
    const int* __restrict__ doff, const int* __restrict__ dcnt,
    _Float16* __restrict__ aggF) {
    int wv = threadIdx.x >> 6, lane = threadIdx.x & 63;
    int dst = blockIdx.x * 4 + wv;
    if (dst >= N_NODES) return;
    int l16 = lane & 15, g = lane >> 4, l8 = lane & 7;
    int beg = doff[dst], cnt = dcnt[dst];

    float m_own = -3e38f, sum_own = 0.f;
    float s0 = 0.f, s1 = 0.f, s2 = 0.f;
    int p0 = 0, p1 = 0, p2 = 0;

    // phase 1: scores, park (s, pr), lane-owned per-rel max
    for (int j0 = 0; j0 < cnt; j0 += 4) {
        int j = j0 + g;
        bool valid = j < cnt;
        int pr = valid ? dpr[beg + j] : 0;
        int src = pr >> 3, rel = pr & 7;
        half8 kv = *(const half8*)(kF + (size_t)src * DIM + l16 * 8);
        half8 uv = *(const half8*)(UF + ((size_t)rel * N_NODES + dst) * DIM +
                                   l16 * 8);
        float s = 0.f;
#pragma unroll
        for (int i = 0; i < 8; ++i) s += (float)kv[i] * (float)uv[i];
        s += __shfl_xor(s, 1, 16);
        s += __shfl_xor(s, 2, 16);
        s += __shfl_xor(s, 4, 16);
        s += __shfl_xor(s, 8, 16);
        if (!valid) s = -3e38f;
        int slot = j0 >> 6;            // wave-uniform
        int idx = (j0 >> 2) & 15;      // wave-uniform
        if (l16 == idx) {
            if (slot == 0) { s0 = s; p0 = pr; }
            else if (slot == 1) { s1 = s; p1 = pr; }
            else if (slot == 2) { s2 = s; p2 = pr; }
        }
        if (valid && l8 == rel && s > m_own) m_own = s;
    }
    // merge per-rel max across the 4 groups
    m_own = fmaxf(m_own, __shfl_xor(m_own, 16, 64));
    m_own = fmaxf(m_own, __shfl_xor(m_own, 32, 64));

    // phase 2: ex = valid ? exp(s - m[rel]) : 0; park ex; lane-owned sum
    for (int j0 = 0; j0 < cnt; j0 += 4) {
        int j = j0 + g;
        bool valid = j < cnt;
        int slot = j0 >> 6;
        int idx = (j0 >> 2) & 15;
        float s;
        int pr;
        if (slot < 3) {
            float sv = (slot == 0) ? s0 : (slot == 1) ? s1 : s2;
            int pv = (slot == 0) ? p0 : (slot == 1) ? p1 : p2;
            s = __shfl(sv, idx, 16);
            pr = __shfl(pv, idx, 16);
        } else {  // overflow fallback: recompute (cnt>192 ~ never at deg~10)
            pr = valid ? dpr[beg + j] : 0;
            int src = pr >> 3, rel = pr & 7;
            half8 kv = *(const half8*)(kF + (size_t)src * DIM + l16 * 8);
            half8 uv = *(const half8*)(UF +
                                       ((size_t)rel * N_NODES + dst) * DIM +
                                       l16 * 8);
            s = 0.f;
#pragma unroll
            for (int i = 0; i < 8; ++i) s += (float)kv[i] * (float)uv[i];
            s += __shfl_xor(s, 1, 16);
            s += __shfl_xor(s, 2, 16);
            s += __shfl_xor(s, 4, 16);
            s += __shfl_xor(s, 8, 16);
        }
        int rel = pr & 7;
        float mr = __shfl(m_own, rel, 8);
        float ex = valid ? __expf(s - mr) : 0.f;  // mask padding edges
        if (l16 == idx) {
            if (slot == 0) s0 = ex;
            else if (slot == 1) s1 = ex;
            else if (slot == 2) s2 = ex;
        }
        if (l8 == rel) sum_own += ex;
    }
    // merge per-rel sums; invert once
    sum_own += __shfl_xor(sum_own, 16, 64);
    sum_own += __shfl_xor(sum_own, 32, 64);
    float inv_own = (sum_own > 0.f) ? 1.f / sum_own : 0.f;

    // phase 3: acc += alpha * VM[rel][src]  (parked ex is already 0 for pads)
    float acc[8] = {0.f, 0.f, 0.f, 0.f, 0.f, 0.f, 0.f, 0.f};
    for (int j0 = 0; j0 < cnt; j0 += 4) {
        int j = j0 + g;
        bool valid = j < cnt;
        int slot = j0 >> 6;
        int idx = (j0 >> 2) & 15;
        float ex;
        int pr;
        if (slot < 3) {
            float sv = (slot == 0) ? s0 : (slot == 1) ? s1 : s2;
            int pv = (slot == 0) ? p0 : (slot == 1) ? p1 : p2;
            ex = __shfl(sv, idx, 16);
            pr = __shfl(pv, idx, 16);
        } else {
            pr = valid ? dpr[beg + j] : 0;
            int src = pr >> 3, rel = pr & 7;
            half8 kv = *(const half8*)(kF + (size_t)src * DIM + l16 * 8);
            half8 uv = *(const half8*)(UF +
                                       ((size_t)rel * N_NODES + dst) * DIM +
                                       l16 * 8);
            float s = 0.f;
#pragma unroll
            for (int i = 0; i < 8; ++i) s += (float)kv[i] * (float)uv[i];
            s += __shfl_xor(s, 1, 16);
            s += __shfl_xor(s, 2, 16);
            s += __shfl_xor(s, 4, 16);
            s += __shfl_xor(s, 8, 16);
            float mr = __shfl(m_own, (pr & 7), 8);
            ex = valid ? __expf(s - mr) : 0.f;
        }
        int rel = pr & 7, src = pr >> 3;
        float alpha = ex * __shfl(inv_own, rel, 8);
        half8 v = *(const half8*)(VMF + ((size_t)rel * N_NODES + src) * DIM +
                                  l16 * 8);
#pragma unroll
        for (int i = 0; i < 8; ++i) acc[i] += alpha * (float)v[i];
    }
    // merge acc across the 4 groups (each covers the full 128 dims)
#pragma unroll
    for (int i = 0; i < 8; ++i) {
        acc[i] += __shfl_xor(acc[i], 16, 64);
        acc[i] += __shfl_xor(acc[i], 32, 64);
    }
    if (g == 0) {
        half8 o;
#pragma unroll
        for (int i = 0; i < 8; ++i) o[i] = (_Float16)acc[i];
        *(half8*)(aggF + (size_t)dst * DIM + l16 * 8) = o;
    }
}

// out: 128-node type-uniform chunk MFMA GEMM, fp32 stores with sigmoid gate
__global__ __launch_bounds__(256) void out_kernel(
    const _Float16* __restrict__ aggF, const int* __restrict__ ntype,
    const _Float16* __restrict__ WaT, const float* __restrict__ skip,
    const int* __restrict__ nlist, float* __restrict__ out) {
    __shared__ int nid[128];
    int tid = threadIdx.x;
    if (tid < 128) nid[tid] = nlist[blockIdx.x * 128 + tid];
    __syncthreads();
    if (nid[0] < 0) return;
    int t = ntype[nid[0]];
    float sig = 1.f / (1.f + __expf(-skip[t]));
    int wv = tid >> 6, lane = tid & 63, l16 = lane & 15, quad = lane >> 4;
    int r0 = wv * 32;
    int nA[2];
#pragma unroll
    for (int m = 0; m < 2; ++m) nA[m] = nid[r0 + m * 16 + l16];
    const _Float16* B = WaT + (t << 14);
    f32x4 acc[2][8];
#pragma unroll
    for (int m = 0; m < 2; ++m)
#pragma unroll
        for (int c = 0; c < 8; ++c) acc[m][c] = (f32x4){0.f, 0.f, 0.f, 0.f};
    for (int kk = 0; kk < 4; ++kk) {
        int kb = kk * 32 + quad * 8;
        half8 a[2];
#pragma unroll
        for (int m = 0; m < 2; ++m)
            a[m] = (nA[m] >= 0)
                       ? *(const half8*)(aggF + (size_t)nA[m] * DIM + kb)
                       : (half8){0, 0, 0, 0, 0, 0, 0, 0};
#pragma unroll
        for (int c = 0; c < 8; ++c) {
            half8 b = *(const half8*)(B + (c * 16 + l16) * DIM + kb);
#pragma unroll
            for (int m = 0; m < 2; ++m)
                acc[m][c] = __builtin_amdgcn_mfma_f32_16x16x32_f16(
                    a[m], b, acc[m][c], 0, 0, 0);
        }
    }
#pragma unroll
    for (int m = 0; m < 2; ++m)
#pragma unroll
        for (int c = 0; c < 8; ++c)
#pragma unroll
            for (int rg = 0; rg < 4; ++rg) {
                int node = nid[r0 + m * 16 + quad * 4 + rg];
                if (node >= 0)
                    out[(size_t)node * DIM + c * 16 + l16] =
                        acc[m][c][rg] * sig;
            }
}

extern "C" void kernel_launch(void* const* d_in, const int* in_sizes, int n_in,
                              void* d_out, int out_size, void* d_ws,
                              size_t ws_size, hipStream_t stream) {
    const float* h = (const float*)d_in[0];
    const int* adj = (const int*)d_in[1];
    const int* etype = (const int*)d_in[2];
    const int* ntype = (const int*)d_in[3];
    const float* Wk = (const float*)d_in[6];
    const float* Wq = (const float*)d_in[7];
    const float* Wv = (const float*)d_in[8];
    const float* Wa = (const float*)d_in[9];
    const float* pri = (const float*)d_in[10];
    const float* att = (const float*)d_in[11];
    const float* msg = (const float*)d_in[12];
    const float* skip = (const float*)d_in[13];
    float* out = (float*)d_out;

    int* wsi = (int*)d_ws + OFF_INT;
    _Float16* wsh = (_Float16*)d_ws;
    _Float16* UF = wsh + (size_t)OFF_U * 2;
    _Float16* hF = wsh + (size_t)OFF_HF * 2;
    _Float16* VMF = wsh + (size_t)OFF_VM * 2;
    _Float16* qF = wsh + (size_t)OFF_QF * 2;
    _Float16* kF = wsh + (size_t)OFF_KF * 2;
    _Float16* aggF = wsh + (size_t)OFF_AGGF * 2;
    _Float16* vF = wsh + (size_t)OFF_VF * 2;
    _Float16* attF = wsh + (size_t)OFF_ATTF * 2;
    _Float16* msgT = wsh + (size_t)OFF_MSGT * 2;
    _Float16* WvT = wsh + (size_t)OFF_WVT * 2;
    _Float16* WaT = wsh + (size_t)OFF_WAT * 2;

    init_kernel<<<(100000 + 255) / 256, 256, 0, stream>>>(wsi);
    convert_kernel<<<(RR * DIM * DIM + 255) / 256, 256, 0, stream>>>(
        att, msg, Wv, Wa, attF, msgT, WvT, WaT);
    hconv_kernel<<<(N_NODES * DIM / 4 + 255) / 256, 256, 0, stream>>>(h, hF);
    hist_kernel<<<GRID_E, 256, 0, stream>>>(ntype, adj, wsi);
    offsets_kernel<<<1, 1, 0, stream>>>(wsi);
    scanA_kernel<<<SCAN_BLOCKS, 256, 0, stream>>>(wsi);
    scanB_kernel<<<1, 256, 0, stream>>>(wsi);
    scanC_kernel<<<SCAN_BLOCKS, 256, 0, stream>>>(wsi);
    scatter_kernel<<<GRID_E, 256, 0, stream>>>(ntype, etype, adj, wsi);
    kq_f32_kernel<<<CHUNK_GRID * 4, 256, 0, stream>>>(h, ntype, Wk, Wq,
                                                      wsi + IO_NLIST, kF, qF);
    vproj_kernel<<<CHUNK_GRID, 256, 0, stream>>>(hF, ntype, WvT,
                                                 wsi + IO_NLIST, vF);
    // U pass (reads qF) fully precedes VM pass (writes VMF; qF aliases
    // VMF[7]) — stream ordering guarantees no overlap.
    nr_gemm3_kernel<<<RR * NR3_CHUNKS, 256, 0, stream>>>(qF, attF, UF, pri, 1);
    nr_gemm3_kernel<<<RR * NR3_CHUNKS, 256, 0, stream>>>(vF, msgT, VMF, pri, 0);
    attend_kernel<<<(N_NODES + 3) / 4, 256, 0, stream>>>(
        kF, UF, VMF, wsi + IO_DPR, wsi + IO_DOFF, wsi + IO_DCNT, aggF);
    out_kernel<<<CHUNK_GRID, 256, 0, stream>>>(aggF, ntype, WaT, skip,
                                               wsi + IO_NLIST, out);
}

// Round 6
// 392.262 us; speedup vs baseline: 1.3374x; 1.0103x over previous
//
#include <hip/hip_runtime.h>
#include <math.h>

// ---------------------------------------------------------------------------
// HGT layer slice. R17 (resubmit; R5 bench was an infra failure — container
// died twice, kernel never measured): kq_f32 software pipeline (4x k-loop
// unroll + vector LDS reads). R16 post-mortem: nr_gemm fixed (B register-
// resident; out of top-5); kq_f32 now leads at 72.6us with VALUBusy 37% vs
// a 21us issue floor — latency-bound on the 1-deep W-load chain. Fix:
// unroll i by 4, batch 4 W float4 loads + 4 ds_read_b128 (hl rows 528B =
// 16B aligned, broadcast reads) per 64 FMAs. Accumulation order per acc
// unchanged -> bit-exact (score path stays argmax-safe).
//
// nr_gemm v6 (R16): register-resident B, streamed A, 2 launches, XCD
// co-location. attend v2.1 (R9), parallel scan (R10), [rel][node] layout
// (R12), qF=VMF[7] alias (R14).
// ---------------------------------------------------------------------------

#define N_NODES 50000
#define N_EDGES 500000
#define DIM 128
#define TT 8
#define RR 8
#define RSQRT_DK 0.08838834764831845f

#define CHUNK_GRID 399               // 399*128 = 51072 >= 50000 + 8*127
#define NODE_LIST_LEN (CHUNK_GRID * 128)
#define GRID_E ((N_EDGES + 255) / 256)   // 1954, also covers N
#define SCAN_BLOCKS ((N_NODES + 255) / 256)   // 196

// nr_gemm v6 geometry: 112 chunks x 448 rows (7 iters x 64) = 50176 >= 50000
// 112 % 8 == 0 -> blocks rel*112+c land on xcd = c%8 for every rel.
#define NR3_CHUNKS 112
#define NR3_ROWS 448
#define NR3_ITERS 7

// word offsets (4B units); _Float16 index = 2*word
#define OFF_U 0                    // UF16 [rel][n][128]
#define OFF_HF 0                   // alias: hF16 [n][128] (dead before U write)
#define OFF_VM 25600000            // VMF16 [rel][n][128]
#define OFF_QF 48000000            // alias: qF16 = VMF[rel=7] slice.
                                   // SAFE: U launch (reads qF) completes
                                   // before VM launch (writes VMF) starts —
                                   // separate kernels, stream-ordered.
#define OFF_KF 51200000
#define OFF_AGGF 54400000
#define OFF_VF 54400000            // alias: vF16 (dead before attend writes agg)
#define OFF_ATTF 57600000          // 65,536 words each, 100k spacing
#define OFF_MSGT 57700000
#define OFF_WVT 57800000
#define OFF_WAT 57900000
#define OFF_INT 58000000           // int region, +701,872 -> 58,701,872 words
#define IO_NLIST 0                 // 51,072
#define IO_CNT_N 51072
#define IO_CUR_N 51080
#define IO_POFF_N 51088
#define IO_DCNT 51104              // 50,000
#define IO_DCUR 101104             // 50,000
#define IO_DOFF 151104             // 50,000
#define IO_DPR 201104              // 500,000 packed (src*8|rel) per CSR slot
#define IO_BLKSUM 701104           // 256 per-scan-block totals
#define IO_BLKOFF 701360           // 256 scanned block offsets; end 701,616

typedef _Float16 half8 __attribute__((ext_vector_type(8)));
typedef _Float16 half4 __attribute__((ext_vector_type(4)));
typedef float f32x4 __attribute__((ext_vector_type(4)));

__global__ void init_kernel(int* wsi) {
    int i = blockIdx.x * blockDim.x + threadIdx.x;
    if (i < NODE_LIST_LEN) wsi[IO_NLIST + i] = -1;
    if (i < 32) wsi[IO_CNT_N + i] = 0;
    if (i < 100000) wsi[IO_DCNT + i] = 0;  // dcnt + dcur contiguous
}

// attF straight [r][d][f]; msgT/WvT/WaT transposed to [.][f][d], all f16
__global__ void convert_kernel(const float* __restrict__ att,
                               const float* __restrict__ msg,
                               const float* __restrict__ Wv,
                               const float* __restrict__ Wa,
                               _Float16* __restrict__ attF,
                               _Float16* __restrict__ msgT,
                               _Float16* __restrict__ WvT,
                               _Float16* __restrict__ WaT) {
    int i = blockIdx.x * 256 + threadIdx.x;
    if (i >= RR * DIM * DIM) return;
    int td = i >> 14, d = (i >> 7) & 127, f = i & 127;
    int tr = (td << 14) + (f << 7) + d;
    attF[i] = (_Float16)att[i];
    msgT[tr] = (_Float16)msg[i];
    WvT[tr] = (_Float16)Wv[i];
    WaT[tr] = (_Float16)Wa[i];
}

__global__ void hconv_kernel(const float* __restrict__ h,
                             _Float16* __restrict__ hF) {
    int i = blockIdx.x * 256 + threadIdx.x;
    if (i < N_NODES * DIM / 4) {
        float4 v = ((const float4*)h)[i];
        half4 o;
        o[0] = (_Float16)v.x; o[1] = (_Float16)v.y;
        o[2] = (_Float16)v.z; o[3] = (_Float16)v.w;
        *(half4*)(hF + (size_t)i * 4) = o;
    }
}

__global__ void hist_kernel(const int* __restrict__ ntype,
                            const int* __restrict__ adj, int* wsi) {
    __shared__ int cn[TT];
    int tid = threadIdx.x;
    if (tid < TT) cn[tid] = 0;
    __syncthreads();
    int i = blockIdx.x * blockDim.x + tid;
    if (i < N_NODES) atomicAdd(&cn[ntype[i]], 1);
    if (i < N_EDGES) atomicAdd(&wsi[IO_DCNT + adj[N_EDGES + i]], 1);
    __syncthreads();
    if (tid < TT && cn[tid] > 0) atomicAdd(&wsi[IO_CNT_N + tid], cn[tid]);
}

__global__ void offsets_kernel(int* wsi) {
    int off = 0;
    for (int t = 0; t < TT; ++t) {
        wsi[IO_POFF_N + t] = off;
        off += ((wsi[IO_CNT_N + t] + 127) >> 7) << 7;  // pad to 128
    }
}

// 3-phase parallel exclusive scan of the 50k dst counts
__global__ __launch_bounds__(256) void scanA_kernel(int* wsi) {
    __shared__ int tmp[256];
    int tid = threadIdx.x;
    int i = blockIdx.x * 256 + tid;
    int v = (i < N_NODES) ? wsi[IO_DCNT + i] : 0;
    tmp[tid] = v;
    __syncthreads();
    for (int off = 1; off < 256; off <<= 1) {
        int t = (tid >= off) ? tmp[tid - off] : 0;
        __syncthreads();
        tmp[tid] += t;
        __syncthreads();
    }
    if (i < N_NODES) wsi[IO_DOFF + i] = tmp[tid] - v;  // block-local exclusive
    if (tid == 255) wsi[IO_BLKSUM + blockIdx.x] = tmp[255];
}

__global__ __launch_bounds__(256) void scanB_kernel(int* wsi) {
    __shared__ int tmp[256];
    int tid = threadIdx.x;
    int v = (tid < SCAN_BLOCKS) ? wsi[IO_BLKSUM + tid] : 0;
    tmp[tid] = v;
    __syncthreads();
    for (int off = 1; off < 256; off <<= 1) {
        int t = (tid >= off) ? tmp[tid - off] : 0;
        __syncthreads();
        tmp[tid] += t;
        __syncthreads();
    }
    wsi[IO_BLKOFF + tid] = tmp[tid] - v;
}

__global__ __launch_bounds__(256) void scanC_kernel(int* wsi) {
    int i = blockIdx.x * 256 + threadIdx.x;
    if (i < N_NODES) wsi[IO_DOFF + i] += wsi[IO_BLKOFF + blockIdx.x];
}

__global__ void scatter_kernel(const int* __restrict__ ntype,
                               const int* __restrict__ etype,
                               const int* __restrict__ adj, int* wsi) {
    __shared__ int cn[TT], bn[TT];
    int tid = threadIdx.x;
    if (tid < TT) cn[tid] = 0;
    __syncthreads();
    int i = blockIdx.x * blockDim.x + tid;
    int t = -1, rnk = 0;
    if (i < N_NODES) {
        t = ntype[i];
        rnk = atomicAdd(&cn[t], 1);
    }
    __syncthreads();
    if (tid < TT && cn[tid] > 0) bn[tid] = atomicAdd(&wsi[IO_CUR_N + tid], cn[tid]);
    __syncthreads();
    if (t >= 0)
        wsi[IO_NLIST + wsi[IO_POFF_N + t] + bn[t] + rnk] = i;
    if (i < N_EDGES) {
        int d = adj[N_EDGES + i];
        int pos = wsi[IO_DOFF + d] + atomicAdd(&wsi[IO_DCUR + d], 1);
        wsi[IO_DPR + pos] = (adj[i] << 3) | etype[i];  // packed src*8|rel
    }
}

// k,q: fp32 vector tile GEMM (score path is argmax-sensitive; R6 post-mortem)
// R17: i-loop unrolled x4 with batched W float4 loads + ds_read_b128 hl
// reads. Per-acc accumulation order unchanged -> bit-exact vs R16.
__global__ __launch_bounds__(256) void kq_f32_kernel(
    const float* __restrict__ h, const int* __restrict__ ntype,
    const float* __restrict__ Wk, const float* __restrict__ Wq,
    const int* __restrict__ nlist, _Float16* __restrict__ kout,
    _Float16* __restrict__ qout) {
    __shared__ float hl[32][DIM + 4];
    __shared__ int nid[32];
    int tid = threadIdx.x;
    int base = blockIdx.x * 32;
    if (tid < 32) nid[tid] = nlist[base + tid];
    __syncthreads();
    if (nid[0] < 0) return;
    int t = ntype[nid[0]];

    for (int r2 = 0; r2 < 32; r2 += 2) {
        int row = r2 + (tid >> 7);
        int col = tid & 127;
        int n = nid[row];
        if (n < 0) n = 0;
        hl[row][col] = h[(size_t)n * DIM + col];
    }
    __syncthreads();
    int te = tid >> 5, tc = tid & 31;

#pragma unroll
    for (int w = 0; w < 2; ++w) {
        const float* W = (w == 0 ? Wk : Wq) + (size_t)t * DIM * DIM;
        const float4* W4 = (const float4*)W;
        _Float16* O = (w == 0 ? kout : qout);
        float acc[4][4] = {};
        for (int i = 0; i < DIM; i += 4) {
            // batch 4 W-row fragments (coalesced 16B/lane) ...
            float4 a0 = W4[(i + 0) * 32 + tc];
            float4 a1 = W4[(i + 1) * 32 + tc];
            float4 a2 = W4[(i + 2) * 32 + tc];
            float4 a3 = W4[(i + 3) * 32 + tc];
#pragma unroll
            for (int j = 0; j < 4; ++j) {
                // ... and 4 h values per node as one ds_read_b128
                // (hl row = 528B, 16B-aligned; address lane-uniform per
                // te-group -> broadcast, conflict-free)
                float4 hv = *(const float4*)&hl[te * 4 + j][i];
                acc[j][0] += hv.x * a0.x;
                acc[j][1] += hv.x * a0.y;
                acc[j][2] += hv.x * a0.z;
                acc[j][3] += hv.x * a0.w;
                acc[j][0] += hv.y * a1.x;
                acc[j][1] += hv.y * a1.y;
                acc[j][2] += hv.y * a1.z;
                acc[j][3] += hv.y * a1.w;
                acc[j][0] += hv.z * a2.x;
                acc[j][1] += hv.z * a2.y;
                acc[j][2] += hv.z * a2.z;
                acc[j][3] += hv.z * a2.w;
                acc[j][0] += hv.w * a3.x;
                acc[j][1] += hv.w * a3.y;
                acc[j][2] += hv.w * a3.z;
                acc[j][3] += hv.w * a3.w;
            }
        }
#pragma unroll
        for (int j = 0; j < 4; ++j) {
            int n = nid[te * 4 + j];
            if (n >= 0) {
                half4 o;
                o[0] = (_Float16)acc[j][0];
                o[1] = (_Float16)acc[j][1];
                o[2] = (_Float16)acc[j][2];
                o[3] = (_Float16)acc[j][3];
                *(half4*)(O + (size_t)n * DIM + tc * 4) = o;
            }
        }
    }
}

// v: 128-node type-uniform chunk MFMA GEMM (value path: f16-tolerant)
__global__ __launch_bounds__(256) void vproj_kernel(
    const _Float16* __restrict__ hF, const int* __restrict__ ntype,
    const _Float16* __restrict__ WvT, const int* __restrict__ nlist,
    _Float16* __restrict__ vout) {
    __shared__ int nid[128];
    int tid = threadIdx.x;
    if (tid < 128) nid[tid] = nlist[blockIdx.x * 128 + tid];
    __syncthreads();
    if (nid[0] < 0) return;
    int t = ntype[nid[0]];
    int wv = tid >> 6, lane = tid & 63, l16 = lane & 15, quad = lane >> 4;
    int r0 = wv * 32;
    int nA[2];
#pragma unroll
    for (int m = 0; m < 2; ++m) nA[m] = nid[r0 + m * 16 + l16];
    const _Float16* B = WvT + (t << 14);
    f32x4 acc[2][8];
#pragma unroll
    for (int m = 0; m < 2; ++m)
#pragma unroll
        for (int c = 0; c < 8; ++c) acc[m][c] = (f32x4){0.f, 0.f, 0.f, 0.f};
    for (int kk = 0; kk < 4; ++kk) {
        int kb = kk * 32 + quad * 8;
        half8 a[2];
#pragma unroll
        for (int m = 0; m < 2; ++m)
            a[m] = (nA[m] >= 0)
                       ? *(const half8*)(hF + (size_t)nA[m] * DIM + kb)
                       : (half8){0, 0, 0, 0, 0, 0, 0, 0};
#pragma unroll
        for (int c = 0; c < 8; ++c) {
            half8 b = *(const half8*)(B + (c * 16 + l16) * DIM + kb);
#pragma unroll
            for (int m = 0; m < 2; ++m)
                acc[m][c] = __builtin_amdgcn_mfma_f32_16x16x32_f16(
                    a[m], b, acc[m][c], 0, 0, 0);
        }
    }
#pragma unroll
    for (int m = 0; m < 2; ++m)
#pragma unroll
        for (int c = 0; c < 8; ++c)
#pragma unroll
            for (int rg = 0; rg < 4; ++rg) {
                int node = nid[r0 + m * 16 + quad * 4 + rg];
                if (node >= 0)
                    vout[(size_t)node * DIM + c * 16 + l16] =
                        (_Float16)acc[m][c][rg];
            }
}

// ---------------------------------------------------------------------------
// nr_gemm v6 (R16-proven): one block = one rel; B register-resident; stream
// NR3_ITERS x 64-row tiles with double-buffered A prefetch.
// ---------------------------------------------------------------------------
__global__ __launch_bounds__(256, 2) void nr_gemm3_kernel(
    const _Float16* __restrict__ A, const _Float16* __restrict__ B8,
    _Float16* __restrict__ Out, const float* __restrict__ pri, int isU) {
    __shared__ _Float16 stage[4][16][136];
    int bid = blockIdx.x;
    int rel = bid / NR3_CHUNKS;
    int chunk = bid - rel * NR3_CHUNKS;
    float scale = isU ? pri[rel] * RSQRT_DK : 1.0f;
    const _Float16* Bb = B8 + (rel << 14);
    int tid = threadIdx.x;
    int wv = tid >> 6, lane = tid & 63;
    int l16 = lane & 15, quad = lane >> 4;

    // B fragments once: bfrag[c][kk] covers B-row c*16+l16, k=kk*32+quad*8
    half8 bfrag[8][4];
#pragma unroll
    for (int c = 0; c < 8; ++c)
#pragma unroll
        for (int kk = 0; kk < 4; ++kk)
            bfrag[c][kk] =
                *(const half8*)(Bb + (c * 16 + l16) * DIM + kk * 32 + quad * 8);

    _Float16* Orel = Out + (size_t)rel * N_NODES * DIM;
    int base = chunk * NR3_ROWS + wv * 16;  // this wave's first tile row

    // prefetch tile 0
    half8 aNow[4], aNext[4];
    {
        int nodeA = base + l16;
#pragma unroll
        for (int kk = 0; kk < 4; ++kk)
            aNow[kk] = (nodeA < N_NODES)
                           ? *(const half8*)(A + (size_t)nodeA * DIM +
                                             kk * 32 + quad * 8)
                           : (half8){0, 0, 0, 0, 0, 0, 0, 0};
    }

    for (int it = 0; it < NR3_ITERS; ++it) {
        int row0 = base + it * 64;
        // prefetch next tile's A while this tile computes
        if (it + 1 < NR3_ITERS) {
            int nodeA = row0 + 64 + l16;
#pragma unroll
            for (int kk = 0; kk < 4; ++kk)
                aNext[kk] = (nodeA < N_NODES)
                                ? *(const half8*)(A + (size_t)nodeA * DIM +
                                                  kk * 32 + quad * 8)
                                : (half8){0, 0, 0, 0, 0, 0, 0, 0};
        }
        f32x4 acc[8];
#pragma unroll
        for (int c = 0; c < 8; ++c) acc[c] = (f32x4){0.f, 0.f, 0.f, 0.f};
#pragma unroll
        for (int kk = 0; kk < 4; ++kk)
#pragma unroll
            for (int c = 0; c < 8; ++c)
                acc[c] = __builtin_amdgcn_mfma_f32_16x16x32_f16(
                    bfrag[c][kk], aNow[kk], acc[c], 0, 0, 0);
        // stage transposed acc into wave-private LDS: row = local node l16,
        // feature = c*16 + quad*4 + rg
#pragma unroll
        for (int c = 0; c < 8; ++c) {
            half4 o;
#pragma unroll
            for (int rg = 0; rg < 4; ++rg)
                o[rg] = (_Float16)(acc[c][rg] * scale);
            *(half4*)&stage[wv][l16][c * 16 + quad * 4] = o;
        }
        // read back row-wise: 4 x (4 rows x 256B) = 1KiB contiguous stores
        _Float16* Op = Orel + (size_t)row0 * DIM;
#pragma unroll
        for (int s = 0; s < 4; ++s) {
            int row = s * 4 + quad;
            if (row0 + row < N_NODES) {
                half8 v = *(const half8*)&stage[wv][row][l16 * 8];
                *(half8*)(Op + (size_t)row * DIM + l16 * 8) = v;
            }
        }
#pragma unroll
        for (int kk = 0; kk < 4; ++kk) aNow[kk] = aNext[kk];
    }
}

// ---------------------------------------------------------------------------
// attend v2.1 (R9-proven); U/VM indexed [rel][node][128] (R12 relayout).
// ---------------------------------------------------------------------------
__global__ __launch_bounds__(256) void attend_kernel(
    const _Float16* __restrict__ kF, const _Float16* __restrict__ UF,
    const _Float16* __restrict__ VMF, const int* __restrict__ dpr,
    const int* __restrict__ doff, const int* __restrict__ dcnt,
    _Float16* __restrict__ aggF) {
    int wv = threadIdx.x >> 6, lane = threadIdx.x & 63;
    int dst = blockIdx.x * 4 + wv;
    if (dst >= N_NODES) return;
    int l16 = lane & 15, g = lane >> 4, l8 = lane & 7;
    int beg = doff[dst], cnt = dcnt[dst];

    float m_own = -3e38f, sum_own = 0.f;
    float s0 = 0.f, s1 = 0.f, s2 = 0.f;
    int p0 = 0, p1 = 0, p2 = 0;

    // phase 1: scores, park (s, pr), lane-owned per-rel max
    for (int j0 = 0; j0 < cnt; j0 += 4) {
        int j = j0 + g;
        bool valid = j < cnt;
        int pr = valid ? dpr[beg + j] : 0;
        int src = pr >> 3, rel = pr & 7;
        half8 kv = *(const half8*)(kF + (size_t)src * DIM + l16 * 8);
        half8 uv = *(const half8*)(UF + ((size_t)rel * N_NODES + dst) * DIM +
                                   l16 * 8);
        float s = 0.f;
#pragma unroll
        for (int i = 0; i < 8; ++i) s += (float)kv[i] * (float)uv[i];
        s += __shfl_xor(s, 1, 16);
        s += __shfl_xor(s, 2, 16);
        s += __shfl_xor(s, 4, 16);
        s += __shfl_xor(s, 8, 16);
        if (!valid) s = -3e38f;
        int slot = j0 >> 6;            // wave-uniform
        int idx = (j0 >> 2) & 15;      // wave-uniform
        if (l16 == idx) {
            if (slot == 0) { s0 = s; p0 = pr; }
            else if (slot == 1) { s1 = s; p1 = pr; }
            else if (slot == 2) { s2 = s; p2 = pr; }
        }
        if (valid && l8 == rel && s > m_own) m_own = s;
    }
    // merge per-rel max across the 4 groups
    m_own = fmaxf(m_own, __shfl_xor(m_own, 16, 64));
    m_own = fmaxf(m_own, __shfl_xor(m_own, 32, 64));

    // phase 2: ex = valid ? exp(s - m[rel]) : 0; park ex; lane-owned sum
    for (int j0 = 0; j0 < cnt; j0 += 4) {
        int j = j0 + g;
        bool valid = j < cnt;
        int slot = j0 >> 6;
        int idx = (j0 >> 2) & 15;
        float s;
        int pr;
        if (slot < 3) {
            float sv = (slot == 0) ? s0 : (slot == 1) ? s1 : s2;
            int pv = (slot == 0) ? p0 : (slot == 1) ? p1 : p2;
            s = __shfl(sv, idx, 16);
            pr = __shfl(pv, idx, 16);
        } else {  // overflow fallback: recompute (cnt>192 ~ never at deg~10)
            pr = valid ? dpr[beg + j] : 0;
            int src = pr >> 3, rel = pr & 7;
            half8 kv = *(const half8*)(kF + (size_t)src * DIM + l16 * 8);
            half8 uv = *(const half8*)(UF +
                                       ((size_t)rel * N_NODES + dst) * DIM +
                                       l16 * 8);
            s = 0.f;
#pragma unroll
            for (int i = 0; i < 8; ++i) s += (float)kv[i] * (float)uv[i];
            s += __shfl_xor(s, 1, 16);
            s += __shfl_xor(s, 2, 16);
            s += __shfl_xor(s, 4, 16);
            s += __shfl_xor(s, 8, 16);
        }
        int rel = pr & 7;
        float mr = __shfl(m_own, rel, 8);
        float ex = valid ? __expf(s - mr) : 0.f;  // mask padding edges
        if (l16 == idx) {
            if (slot == 0) s0 = ex;
            else if (slot == 1) s1 = ex;
            else if (slot == 2) s2 = ex;
        }
        if (l8 == rel) sum_own += ex;
    }
    // merge per-rel sums; invert once
    sum_own += __shfl_xor(sum_own, 16, 64);
    sum_own += __shfl_xor(sum_own, 32, 64);
    float inv_own = (sum_own > 0.f) ? 1.f / sum_own : 0.f;

    // phase 3: acc += alpha * VM[rel][src]  (parked ex is already 0 for pads)
    float acc[8] = {0.f, 0.f, 0.f, 0.f, 0.f, 0.f, 0.f, 0.f};
    for (int j0 = 0; j0 < cnt; j0 += 4) {
        int j = j0 + g;
        bool valid = j < cnt;
        int slot = j0 >> 6;
        int idx = (j0 >> 2) & 15;
        float ex;
        int pr;
        if (slot < 3) {
            float sv = (slot == 0) ? s0 : (slot == 1) ? s1 : s2;
            int pv = (slot == 0) ? p0 : (slot == 1) ? p1 : p2;
            ex = __shfl(sv, idx, 16);
            pr = __shfl(pv, idx, 16);
        } else {
            pr = valid ? dpr[beg + j] : 0;
            int src = pr >> 3, rel = pr & 7;
            half8 kv = *(const half8*)(kF + (size_t)src * DIM + l16 * 8);
            half8 uv = *(const half8*)(UF +
                                       ((size_t)rel * N_NODES + dst) * DIM +
                                       l16 * 8);
            float s = 0.f;
#pragma unroll
            for (int i = 0; i < 8; ++i) s += (float)kv[i] * (float)uv[i];
            s += __shfl_xor(s, 1, 16);
            s += __shfl_xor(s, 2, 16);
            s += __shfl_xor(s, 4, 16);
            s += __shfl_xor(s, 8, 16);
            float mr = __shfl(m_own, (pr & 7), 8);
            ex = valid ? __expf(s - mr) : 0.f;
        }
        int rel = pr & 7, src = pr >> 3;
        float alpha = ex * __shfl(inv_own, rel, 8);
        half8 v = *(const half8*)(VMF + ((size_t)rel * N_NODES + src) * DIM +
                                  l16 * 8);
#pragma unroll
        for (int i = 0; i < 8; ++i) acc[i] += alpha * (float)v[i];
    }
    // merge acc across the 4 groups (each covers the full 128 dims)
#pragma unroll
    for (int i = 0; i < 8; ++i) {
        acc[i] += __shfl_xor(acc[i], 16, 64);
        acc[i] += __shfl_xor(acc[i], 32, 64);
    }
    if (g == 0) {
        half8 o;
#pragma unroll
        for (int i = 0; i < 8; ++i) o[i] = (_Float16)acc[i];
        *(half8*)(aggF + (size_t)dst * DIM + l16 * 8) = o;
    }
}

// out: 128-node type-uniform chunk MFMA GEMM, fp32 stores with sigmoid gate
__global__ __launch_bounds__(256) void out_kernel(
    const _Float16* __restrict__ aggF, const int* __restrict__ ntype,
    const _Float16* __restrict__ WaT, const float* __restrict__ skip,
    const int* __restrict__ nlist, float* __restrict__ out) {
    __shared__ int nid[128];
    int tid = threadIdx.x;
    if (tid < 128) nid[tid] = nlist[blockIdx.x * 128 + tid];
    __syncthreads();
    if (nid[0] < 0) return;
    int t = ntype[nid[0]];
    float sig = 1.f / (1.f + __expf(-skip[t]));
    int wv = tid >> 6, lane = tid & 63, l16 = lane & 15, quad = lane >> 4;
    int r0 = wv * 32;
    int nA[2];
#pragma unroll
    for (int m = 0; m < 2; ++m) nA[m] = nid[r0 + m * 16 + l16];
    const _Float16* B = WaT + (t << 14);
    f32x4 acc[2][8];
#pragma unroll
    for (int m = 0; m < 2; ++m)
#pragma unroll
        for (int c = 0; c < 8; ++c) acc[m][c] = (f32x4){0.f, 0.f, 0.f, 0.f};
    for (int kk = 0; kk < 4; ++kk) {
        int kb = kk * 32 + quad * 8;
        half8 a[2];
#pragma unroll
        for (int m = 0; m < 2; ++m)
            a[m] = (nA[m] >= 0)
                       ? *(const half8*)(aggF + (size_t)nA[m] * DIM + kb)
                       : (half8){0, 0, 0, 0, 0, 0, 0, 0};
#pragma unroll
        for (int c = 0; c < 8; ++c) {
            half8 b = *(const half8*)(B + (c * 16 + l16) * DIM + kb);
#pragma unroll
            for (int m = 0; m < 2; ++m)
                acc[m][c] = __builtin_amdgcn_mfma_f32_16x16x32_f16(
                    a[m], b, acc[m][c], 0, 0, 0);
        }
    }
#pragma unroll
    for (int m = 0; m < 2; ++m)
#pragma unroll
        for (int c = 0; c < 8; ++c)
#pragma unroll
            for (int rg = 0; rg < 4; ++rg) {
                int node = nid[r0 + m * 16 + quad * 4 + rg];
                if (node >= 0)
                    out[(size_t)node * DIM + c * 16 + l16] =
                        acc[m][c][rg] * sig;
            }
}

extern "C" void kernel_launch(void* const* d_in, const int* in_sizes, int n_in,
                              void* d_out, int out_size, void* d_ws,
                              size_t ws_size, hipStream_t stream) {
    const float* h = (const float*)d_in[0];
    const int* adj = (const int*)d_in[1];
    const int* etype = (const int*)d_in[2];
    const int* ntype = (const int*)d_in[3];
    const float* Wk = (const float*)d_in[6];
    const float* Wq = (const float*)d_in[7];
    const float* Wv = (const float*)d_in[8];
    const float* Wa = (const float*)d_in[9];
    const float* pri = (const float*)d_in[10];
    const float* att = (const float*)d_in[11];
    const float* msg = (const float*)d_in[12];
    const float* skip = (const float*)d_in[13];
    float* out = (float*)d_out;

    int* wsi = (int*)d_ws + OFF_INT;
    _Float16* wsh = (_Float16*)d_ws;
    _Float16* UF = wsh + (size_t)OFF_U * 2;
    _Float16* hF = wsh + (size_t)OFF_HF * 2;
    _Float16* VMF = wsh + (size_t)OFF_VM * 2;
    _Float16* qF = wsh + (size_t)OFF_QF * 2;
    _Float16* kF = wsh + (size_t)OFF_KF * 2;
    _Float16* aggF = wsh + (size_t)OFF_AGGF * 2;
    _Float16* vF = wsh + (size_t)OFF_VF * 2;
    _Float16* attF = wsh + (size_t)OFF_ATTF * 2;
    _Float16* msgT = wsh + (size_t)OFF_MSGT * 2;
    _Float16* WvT = wsh + (size_t)OFF_WVT * 2;
    _Float16* WaT = wsh + (size_t)OFF_WAT * 2;

    init_kernel<<<(100000 + 255) / 256, 256, 0, stream>>>(wsi);
    convert_kernel<<<(RR * DIM * DIM + 255) / 256, 256, 0, stream>>>(
        att, msg, Wv, Wa, attF, msgT, WvT, WaT);
    hconv_kernel<<<(N_NODES * DIM / 4 + 255) / 256, 256, 0, stream>>>(h, hF);
    hist_kernel<<<GRID_E, 256, 0, stream>>>(ntype, adj, wsi);
    offsets_kernel<<<1, 1, 0, stream>>>(wsi);
    scanA_kernel<<<SCAN_BLOCKS, 256, 0, stream>>>(wsi);
    scanB_kernel<<<1, 256, 0, stream>>>(wsi);
    scanC_kernel<<<SCAN_BLOCKS, 256, 0, stream>>>(wsi);
    scatter_kernel<<<GRID_E, 256, 0, stream>>>(ntype, etype, adj, wsi);
    kq_f32_kernel<<<CHUNK_GRID * 4, 256, 0, stream>>>(h, ntype, Wk, Wq,
                                                      wsi + IO_NLIST, kF, qF);
    vproj_kernel<<<CHUNK_GRID, 256, 0, stream>>>(hF, ntype, WvT,
                                                 wsi + IO_NLIST, vF);
    // U pass (reads qF) fully precedes VM pass (writes VMF; qF aliases
    // VMF[7]) — stream ordering guarantees no overlap.
    nr_gemm3_kernel<<<RR * NR3_CHUNKS, 256, 0, stream>>>(qF, attF, UF, pri, 1);
    nr_gemm3_kernel<<<RR * NR3_CHUNKS, 256, 0, stream>>>(vF, msgT, VMF, pri, 0);
    attend_kernel<<<(N_NODES + 3) / 4, 256, 0, stream>>>(
        kF, UF, VMF, wsi + IO_DPR, wsi + IO_DOFF, wsi + IO_DCNT, aggF);
    out_kernel<<<CHUNK_GRID, 256, 0, stream>>>(aggF, ntype, WaT, skip,
                                               wsi + IO_NLIST, out);
}

// Round 7
// 382.530 us; speedup vs baseline: 1.3715x; 1.0254x over previous
//
#include <hip/hip_runtime.h>
#include <math.h>

// ---------------------------------------------------------------------------
// HGT layer slice. R18: kq_f32 v3 — explicit W double-buffer + 64-node blocks.
// R17 post-mortem: unroll alone changed nothing (70us, VALU 37%). VGPR=32 =
// acc(16)+one W-fragment set(16) exactly — compiler recycled load dest regs,
// so the chain stayed load->waitcnt->FMA->load (128cy issue + ~200cy L2 =
// 39% VALU; measured 37%). Fix: (1) cur/nxt double-buffer with
// __launch_bounds__(256,4) so the 2nd buffer gets registers — next loads
// issue BEFORE current FMAs; (2) 64 nodes/block (acc[8][4]) -> 32 FMA/lane
// per W-load (2x), W L2 traffic halved. Accumulation order per acc element
// unchanged (i ascending, same operands) -> bit-exact, argmax-safe.
//
// nr_gemm v6 (R16): register-resident B, streamed A, 2 launches, XCD
// co-location. attend v2.1 (R9), parallel scan (R10), [rel][node] layout
// (R12), qF=VMF[7] alias (R14).
// ---------------------------------------------------------------------------

#define N_NODES 50000
#define N_EDGES 500000
#define DIM 128
#define TT 8
#define RR 8
#define RSQRT_DK 0.08838834764831845f

#define CHUNK_GRID 399               // 399*128 = 51072 >= 50000 + 8*127
#define NODE_LIST_LEN (CHUNK_GRID * 128)
#define GRID_E ((N_EDGES + 255) / 256)   // 1954, also covers N
#define SCAN_BLOCKS ((N_NODES + 255) / 256)   // 196

// nr_gemm v6 geometry: 112 chunks x 448 rows (7 iters x 64) = 50176 >= 50000
// 112 % 8 == 0 -> blocks rel*112+c land on xcd = c%8 for every rel.
#define NR3_CHUNKS 112
#define NR3_ROWS 448
#define NR3_ITERS 7

// word offsets (4B units); _Float16 index = 2*word
#define OFF_U 0                    // UF16 [rel][n][128]
#define OFF_HF 0                   // alias: hF16 [n][128] (dead before U write)
#define OFF_VM 25600000            // VMF16 [rel][n][128]
#define OFF_QF 48000000            // alias: qF16 = VMF[rel=7] slice.
                                   // SAFE: U launch (reads qF) completes
                                   // before VM launch (writes VMF) starts —
                                   // separate kernels, stream-ordered.
#define OFF_KF 51200000
#define OFF_AGGF 54400000
#define OFF_VF 54400000            // alias: vF16 (dead before attend writes agg)
#define OFF_ATTF 57600000          // 65,536 words each, 100k spacing
#define OFF_MSGT 57700000
#define OFF_WVT 57800000
#define OFF_WAT 57900000
#define OFF_INT 58000000           // int region, +701,872 -> 58,701,872 words
#define IO_NLIST 0                 // 51,072
#define IO_CNT_N 51072
#define IO_CUR_N 51080
#define IO_POFF_N 51088
#define IO_DCNT 51104              // 50,000
#define IO_DCUR 101104             // 50,000
#define IO_DOFF 151104             // 50,000
#define IO_DPR 201104              // 500,000 packed (src*8|rel) per CSR slot
#define IO_BLKSUM 701104           // 256 per-scan-block totals
#define IO_BLKOFF 701360           // 256 scanned block offsets; end 701,616

typedef _Float16 half8 __attribute__((ext_vector_type(8)));
typedef _Float16 half4 __attribute__((ext_vector_type(4)));
typedef float f32x4 __attribute__((ext_vector_type(4)));

__global__ void init_kernel(int* wsi) {
    int i = blockIdx.x * blockDim.x + threadIdx.x;
    if (i < NODE_LIST_LEN) wsi[IO_NLIST + i] = -1;
    if (i < 32) wsi[IO_CNT_N + i] = 0;
    if (i < 100000) wsi[IO_DCNT + i] = 0;  // dcnt + dcur contiguous
}

// attF straight [r][d][f]; msgT/WvT/WaT transposed to [.][f][d], all f16
__global__ void convert_kernel(const float* __restrict__ att,
                               const float* __restrict__ msg,
                               const float* __restrict__ Wv,
                               const float* __restrict__ Wa,
                               _Float16* __restrict__ attF,
                               _Float16* __restrict__ msgT,
                               _Float16* __restrict__ WvT,
                               _Float16* __restrict__ WaT) {
    int i = blockIdx.x * 256 + threadIdx.x;
    if (i >= RR * DIM * DIM) return;
    int td = i >> 14, d = (i >> 7) & 127, f = i & 127;
    int tr = (td << 14) + (f << 7) + d;
    attF[i] = (_Float16)att[i];
    msgT[tr] = (_Float16)msg[i];
    WvT[tr] = (_Float16)Wv[i];
    WaT[tr] = (_Float16)Wa[i];
}

__global__ void hconv_kernel(const float* __restrict__ h,
                             _Float16* __restrict__ hF) {
    int i = blockIdx.x * 256 + threadIdx.x;
    if (i < N_NODES * DIM / 4) {
        float4 v = ((const float4*)h)[i];
        half4 o;
        o[0] = (_Float16)v.x; o[1] = (_Float16)v.y;
        o[2] = (_Float16)v.z; o[3] = (_Float16)v.w;
        *(half4*)(hF + (size_t)i * 4) = o;
    }
}

__global__ void hist_kernel(const int* __restrict__ ntype,
                            const int* __restrict__ adj, int* wsi) {
    __shared__ int cn[TT];
    int tid = threadIdx.x;
    if (tid < TT) cn[tid] = 0;
    __syncthreads();
    int i = blockIdx.x * blockDim.x + tid;
    if (i < N_NODES) atomicAdd(&cn[ntype[i]], 1);
    if (i < N_EDGES) atomicAdd(&wsi[IO_DCNT + adj[N_EDGES + i]], 1);
    __syncthreads();
    if (tid < TT && cn[tid] > 0) atomicAdd(&wsi[IO_CNT_N + tid], cn[tid]);
}

__global__ void offsets_kernel(int* wsi) {
    int off = 0;
    for (int t = 0; t < TT; ++t) {
        wsi[IO_POFF_N + t] = off;
        off += ((wsi[IO_CNT_N + t] + 127) >> 7) << 7;  // pad to 128
    }
}

// 3-phase parallel exclusive scan of the 50k dst counts
__global__ __launch_bounds__(256) void scanA_kernel(int* wsi) {
    __shared__ int tmp[256];
    int tid = threadIdx.x;
    int i = blockIdx.x * 256 + tid;
    int v = (i < N_NODES) ? wsi[IO_DCNT + i] : 0;
    tmp[tid] = v;
    __syncthreads();
    for (int off = 1; off < 256; off <<= 1) {
        int t = (tid >= off) ? tmp[tid - off] : 0;
        __syncthreads();
        tmp[tid] += t;
        __syncthreads();
    }
    if (i < N_NODES) wsi[IO_DOFF + i] = tmp[tid] - v;  // block-local exclusive
    if (tid == 255) wsi[IO_BLKSUM + blockIdx.x] = tmp[255];
}

__global__ __launch_bounds__(256) void scanB_kernel(int* wsi) {
    __shared__ int tmp[256];
    int tid = threadIdx.x;
    int v = (tid < SCAN_BLOCKS) ? wsi[IO_BLKSUM + tid] : 0;
    tmp[tid] = v;
    __syncthreads();
    for (int off = 1; off < 256; off <<= 1) {
        int t = (tid >= off) ? tmp[tid - off] : 0;
        __syncthreads();
        tmp[tid] += t;
        __syncthreads();
    }
    wsi[IO_BLKOFF + tid] = tmp[tid] - v;
}

__global__ __launch_bounds__(256) void scanC_kernel(int* wsi) {
    int i = blockIdx.x * 256 + threadIdx.x;
    if (i < N_NODES) wsi[IO_DOFF + i] += wsi[IO_BLKOFF + blockIdx.x];
}

__global__ void scatter_kernel(const int* __restrict__ ntype,
                               const int* __restrict__ etype,
                               const int* __restrict__ adj, int* wsi) {
    __shared__ int cn[TT], bn[TT];
    int tid = threadIdx.x;
    if (tid < TT) cn[tid] = 0;
    __syncthreads();
    int i = blockIdx.x * blockDim.x + tid;
    int t = -1, rnk = 0;
    if (i < N_NODES) {
        t = ntype[i];
        rnk = atomicAdd(&cn[t], 1);
    }
    __syncthreads();
    if (tid < TT && cn[tid] > 0) bn[tid] = atomicAdd(&wsi[IO_CUR_N + tid], cn[tid]);
    __syncthreads();
    if (t >= 0)
        wsi[IO_NLIST + wsi[IO_POFF_N + t] + bn[t] + rnk] = i;
    if (i < N_EDGES) {
        int d = adj[N_EDGES + i];
        int pos = wsi[IO_DOFF + d] + atomicAdd(&wsi[IO_DCUR + d], 1);
        wsi[IO_DPR + pos] = (adj[i] << 3) | etype[i];  // packed src*8|rel
    }
}

// k,q: fp32 vector tile GEMM (score path is argmax-sensitive; R6 post-mortem)
// R18 v3: 64 nodes/block (te-group of 8), explicit cur/nxt double-buffer of
// the 4 W float4 fragments, __launch_bounds__(256,4) for VGPR headroom.
// Accumulation order per acc element unchanged -> bit-exact vs R16/R17.
__global__ __launch_bounds__(256, 4) void kq_f32_kernel(
    const float* __restrict__ h, const int* __restrict__ ntype,
    const float* __restrict__ Wk, const float* __restrict__ Wq,
    const int* __restrict__ nlist, _Float16* __restrict__ kout,
    _Float16* __restrict__ qout) {
    __shared__ float hl[64][DIM + 4];
    __shared__ int nid[64];
    int tid = threadIdx.x;
    int base = blockIdx.x * 64;
    if (tid < 64) nid[tid] = nlist[base + tid];
    __syncthreads();
    if (nid[0] < 0) return;
    int t = ntype[nid[0]];

    for (int r2 = 0; r2 < 64; r2 += 2) {
        int row = r2 + (tid >> 7);
        int col = tid & 127;
        int n = nid[row];
        if (n < 0) n = 0;
        hl[row][col] = h[(size_t)n * DIM + col];
    }
    __syncthreads();
    int te = tid >> 5, tc = tid & 31;   // te-group owns 8 nodes

#pragma unroll
    for (int w = 0; w < 2; ++w) {
        const float* W = (w == 0 ? Wk : Wq) + (size_t)t * DIM * DIM;
        const float4* W4 = (const float4*)W;
        _Float16* O = (w == 0 ? kout : qout);
        float acc[8][4] = {};
        // prefetch i=0 batch
        float4 cur0 = W4[0 * 32 + tc];
        float4 cur1 = W4[1 * 32 + tc];
        float4 cur2 = W4[2 * 32 + tc];
        float4 cur3 = W4[3 * 32 + tc];
        for (int i = 0; i < DIM; i += 4) {
            // issue next batch BEFORE consuming cur (double-buffer; safe
            // wrap-to-0 index on last iter keeps loads in-bounds, unused)
            int ip = (i + 4 < DIM) ? (i + 4) : 0;
            float4 nxt0 = W4[(ip + 0) * 32 + tc];
            float4 nxt1 = W4[(ip + 1) * 32 + tc];
            float4 nxt2 = W4[(ip + 2) * 32 + tc];
            float4 nxt3 = W4[(ip + 3) * 32 + tc];
#pragma unroll
            for (int j = 0; j < 8; ++j) {
                // hl row 528B (16B-aligned), address uniform per te-group
                // -> broadcast ds_read_b128, conflict-free
                float4 hv = *(const float4*)&hl[te * 8 + j][i];
                acc[j][0] += hv.x * cur0.x;
                acc[j][1] += hv.x * cur0.y;
                acc[j][2] += hv.x * cur0.z;
                acc[j][3] += hv.x * cur0.w;
                acc[j][0] += hv.y * cur1.x;
                acc[j][1] += hv.y * cur1.y;
                acc[j][2] += hv.y * cur1.z;
                acc[j][3] += hv.y * cur1.w;
                acc[j][0] += hv.z * cur2.x;
                acc[j][1] += hv.z * cur2.y;
                acc[j][2] += hv.z * cur2.z;
                acc[j][3] += hv.z * cur2.w;
                acc[j][0] += hv.w * cur3.x;
                acc[j][1] += hv.w * cur3.y;
                acc[j][2] += hv.w * cur3.z;
                acc[j][3] += hv.w * cur3.w;
            }
            cur0 = nxt0;
            cur1 = nxt1;
            cur2 = nxt2;
            cur3 = nxt3;
        }
#pragma unroll
        for (int j = 0; j < 8; ++j) {
            int n = nid[te * 8 + j];
            if (n >= 0) {
                half4 o;
                o[0] = (_Float16)acc[j][0];
                o[1] = (_Float16)acc[j][1];
                o[2] = (_Float16)acc[j][2];
                o[3] = (_Float16)acc[j][3];
                *(half4*)(O + (size_t)n * DIM + tc * 4) = o;
            }
        }
    }
}

// v: 128-node type-uniform chunk MFMA GEMM (value path: f16-tolerant)
__global__ __launch_bounds__(256) void vproj_kernel(
    const _Float16* __restrict__ hF, const int* __restrict__ ntype,
    const _Float16* __restrict__ WvT, const int* __restrict__ nlist,
    _Float16* __restrict__ vout) {
    __shared__ int nid[128];
    int tid = threadIdx.x;
    if (tid < 128) nid[tid] = nlist[blockIdx.x * 128 + tid];
    __syncthreads();
    if (nid[0] < 0) return;
    int t = ntype[nid[0]];
    int wv = tid >> 6, lane = tid & 63, l16 = lane & 15, quad = lane >> 4;
    int r0 = wv * 32;
    int nA[2];
#pragma unroll
    for (int m = 0; m < 2; ++m) nA[m] = nid[r0 + m * 16 + l16];
    const _Float16* B = WvT + (t << 14);
    f32x4 acc[2][8];
#pragma unroll
    for (int m = 0; m < 2; ++m)
#pragma unroll
        for (int c = 0; c < 8; ++c) acc[m][c] = (f32x4){0.f, 0.f, 0.f, 0.f};
    for (int kk = 0; kk < 4; ++kk) {
        int kb = kk * 32 + quad * 8;
        half8 a[2];
#pragma unroll
        for (int m = 0; m < 2; ++m)
            a[m] = (nA[m] >= 0)
                       ? *(const half8*)(hF + (size_t)nA[m] * DIM + kb)
                       : (half8){0, 0, 0, 0, 0, 0, 0, 0};
#pragma unroll
        for (int c = 0; c < 8; ++c) {
            half8 b = *(const half8*)(B + (c * 16 + l16) * DIM + kb);
#pragma unroll
            for (int m = 0; m < 2; ++m)
                acc[m][c] = __builtin_amdgcn_mfma_f32_16x16x32_f16(
                    a[m], b, acc[m][c], 0, 0, 0);
        }
    }
#pragma unroll
    for (int m = 0; m < 2; ++m)
#pragma unroll
        for (int c = 0; c < 8; ++c)
#pragma unroll
            for (int rg = 0; rg < 4; ++rg) {
                int node = nid[r0 + m * 16 + quad * 4 + rg];
                if (node >= 0)
                    vout[(size_t)node * DIM + c * 16 + l16] =
                        (_Float16)acc[m][c][rg];
            }
}

// ---------------------------------------------------------------------------
// nr_gemm v6 (R16-proven): one block = one rel; B register-resident; stream
// NR3_ITERS x 64-row tiles with double-buffered A prefetch.
// ---------------------------------------------------------------------------
__global__ __launch_bounds__(256, 2) void nr_gemm3_kernel(
    const _Float16* __restrict__ A, const _Float16* __restrict__ B8,
    _Float16* __restrict__ Out, const float* __restrict__ pri, int isU) {
    __shared__ _Float16 stage[4][16][136];
    int bid = blockIdx.x;
    int rel = bid / NR3_CHUNKS;
    int chunk = bid - rel * NR3_CHUNKS;
    float scale = isU ? pri[rel] * RSQRT_DK : 1.0f;
    const _Float16* Bb = B8 + (rel << 14);
    int tid = threadIdx.x;
    int wv = tid >> 6, lane = tid & 63;
    int l16 = lane & 15, quad = lane >> 4;

    // B fragments once: bfrag[c][kk] covers B-row c*16+l16, k=kk*32+quad*8
    half8 bfrag[8][4];
#pragma unroll
    for (int c = 0; c < 8; ++c)
#pragma unroll
        for (int kk = 0; kk < 4; ++kk)
            bfrag[c][kk] =
                *(const half8*)(Bb + (c * 16 + l16) * DIM + kk * 32 + quad * 8);

    _Float16* Orel = Out + (size_t)rel * N_NODES * DIM;
    int base = chunk * NR3_ROWS + wv * 16;  // this wave's first tile row

    // prefetch tile 0
    half8 aNow[4], aNext[4];
    {
        int nodeA = base + l16;
#pragma unroll
        for (int kk = 0; kk < 4; ++kk)
            aNow[kk] = (nodeA < N_NODES)
                           ? *(const half8*)(A + (size_t)nodeA * DIM +
                                             kk * 32 + quad * 8)
                           : (half8){0, 0, 0, 0, 0, 0, 0, 0};
    }

    for (int it = 0; it < NR3_ITERS; ++it) {
        int row0 = base + it * 64;
        // prefetch next tile's A while this tile computes
        if (it + 1 < NR3_ITERS) {
            int nodeA = row0 + 64 + l16;
#pragma unroll
            for (int kk = 0; kk < 4; ++kk)
                aNext[kk] = (nodeA < N_NODES)
                                ? *(const half8*)(A + (size_t)nodeA * DIM +
                                                  kk * 32 + quad * 8)
                                : (half8){0, 0, 0, 0, 0, 0, 0, 0};
        }
        f32x4 acc[8];
#pragma unroll
        for (int c = 0; c < 8; ++c) acc[c] = (f32x4){0.f, 0.f, 0.f, 0.f};
#pragma unroll
        for (int kk = 0; kk < 4; ++kk)
#pragma unroll
            for (int c = 0; c < 8; ++c)
                acc[c] = __builtin_amdgcn_mfma_f32_16x16x32_f16(
                    bfrag[c][kk], aNow[kk], acc[c], 0, 0, 0);
        // stage transposed acc into wave-private LDS: row = local node l16,
        // feature = c*16 + quad*4 + rg
#pragma unroll
        for (int c = 0; c < 8; ++c) {
            half4 o;
#pragma unroll
            for (int rg = 0; rg < 4; ++rg)
                o[rg] = (_Float16)(acc[c][rg] * scale);
            *(half4*)&stage[wv][l16][c * 16 + quad * 4] = o;
        }
        // read back row-wise: 4 x (4 rows x 256B) = 1KiB contiguous stores
        _Float16* Op = Orel + (size_t)row0 * DIM;
#pragma unroll
        for (int s = 0; s < 4; ++s) {
            int row = s * 4 + quad;
            if (row0 + row < N_NODES) {
                half8 v = *(const half8*)&stage[wv][row][l16 * 8];
                *(half8*)(Op + (size_t)row * DIM + l16 * 8) = v;
            }
        }
#pragma unroll
        for (int kk = 0; kk < 4; ++kk) aNow[kk] = aNext[kk];
    }
}

// ---------------------------------------------------------------------------
// attend v2.1 (R9-proven); U/VM indexed [rel][node][128] (R12 relayout).
// ---------------------------------------------------------------------------
__global__ __launch_bounds__(256) void attend_kernel(
    const _Float16* __restrict__ kF, const _Float16* __restrict__ UF,
    const _Float16* __restrict__ VMF, const int* __restrict__ dpr,
    const int* __restrict__ doff, const int* __restrict__ dcnt,
    _Float16* __restrict__ aggF) {
    int wv = threadIdx.x >> 6, lane = threadIdx.x & 63;
    int dst = blockIdx.x * 4 + wv;
    if (dst >= N_NODES) return;
    int l16 = lane & 15, g = lane >> 4, l8 = lane & 7;
    int beg = doff[dst], cnt = dcnt[dst];

    float m_own = -3e38f, sum_own = 0.f;
    float s0 = 0.f, s1 = 0.f, s2 = 0.f;
    int p0 = 0, p1 = 0, p2 = 0;

    // phase 1: scores, park (s, pr), lane-owned per-rel max
    for (int j0 = 0; j0 < cnt; j0 += 4) {
        int j = j0 + g;
        bool valid = j < cnt;
        int pr = valid ? dpr[beg + j] : 0;
        int src = pr >> 3, rel = pr & 7;
        half8 kv = *(const half8*)(kF + (size_t)src * DIM + l16 * 8);
        half8 uv = *(const half8*)(UF + ((size_t)rel * N_NODES + dst) * DIM +
                                   l16 * 8);
        float s = 0.f;
#pragma unroll
        for (int i = 0; i < 8; ++i) s += (float)kv[i] * (float)uv[i];
        s += __shfl_xor(s, 1, 16);
        s += __shfl_xor(s, 2, 16);
        s += __shfl_xor(s, 4, 16);
        s += __shfl_xor(s, 8, 16);
        if (!valid) s = -3e38f;
        int slot = j0 >> 6;            // wave-uniform
        int idx = (j0 >> 2) & 15;      // wave-uniform
        if (l16 == idx) {
            if (slot == 0) { s0 = s; p0 = pr; }
            else if (slot == 1) { s1 = s; p1 = pr; }
            else if (slot == 2) { s2 = s; p2 = pr; }
        }
        if (valid && l8 == rel && s > m_own) m_own = s;
    }
    // merge per-rel max across the 4 groups
    m_own = fmaxf(m_own, __shfl_xor(m_own, 16, 64));
    m_own = fmaxf(m_own, __shfl_xor(m_own, 32, 64));

    // phase 2: ex = valid ? exp(s - m[rel]) : 0; park ex; lane-owned sum
    for (int j0 = 0; j0 < cnt; j0 += 4) {
        int j = j0 + g;
        bool valid = j < cnt;
        int slot = j0 >> 6;
        int idx = (j0 >> 2) & 15;
        float s;
        int pr;
        if (slot < 3) {
            float sv = (slot == 0) ? s0 : (slot == 1) ? s1 : s2;
            int pv = (slot == 0) ? p0 : (slot == 1) ? p1 : p2;
            s = __shfl(sv, idx, 16);
            pr = __shfl(pv, idx, 16);
        } else {  // overflow fallback: recompute (cnt>192 ~ never at deg~10)
            pr = valid ? dpr[beg + j] : 0;
            int src = pr >> 3, rel = pr & 7;
            half8 kv = *(const half8*)(kF + (size_t)src * DIM + l16 * 8);
            half8 uv = *(const half8*)(UF +
                                       ((size_t)rel * N_NODES + dst) * DIM +
                                       l16 * 8);
            s = 0.f;
#pragma unroll
            for (int i = 0; i < 8; ++i) s += (float)kv[i] * (float)uv[i];
            s += __shfl_xor(s, 1, 16);
            s += __shfl_xor(s, 2, 16);
            s += __shfl_xor(s, 4, 16);
            s += __shfl_xor(s, 8, 16);
        }
        int rel = pr & 7;
        float mr = __shfl(m_own, rel, 8);
        float ex = valid ? __expf(s - mr) : 0.f;  // mask padding edges
        if (l16 == idx) {
            if (slot == 0) s0 = ex;
            else if (slot == 1) s1 = ex;
            else if (slot == 2) s2 = ex;
        }
        if (l8 == rel) sum_own += ex;
    }
    // merge per-rel sums; invert once
    sum_own += __shfl_xor(sum_own, 16, 64);
    sum_own += __shfl_xor(sum_own, 32, 64);
    float inv_own = (sum_own > 0.f) ? 1.f / sum_own : 0.f;

    // phase 3: acc += alpha * VM[rel][src]  (parked ex is already 0 for pads)
    float acc[8] = {0.f, 0.f, 0.f, 0.f, 0.f, 0.f, 0.f, 0.f};
    for (int j0 = 0; j0 < cnt; j0 += 4) {
        int j = j0 + g;
        bool valid = j < cnt;
        int slot = j0 >> 6;
        int idx = (j0 >> 2) & 15;
        float ex;
        int pr;
        if (slot < 3) {
            float sv = (slot == 0) ? s0 : (slot == 1) ? s1 : s2;
            int pv = (slot == 0) ? p0 : (slot == 1) ? p1 : p2;
            ex = __shfl(sv, idx, 16);
            pr = __shfl(pv, idx, 16);
        } else {
            pr = valid ? dpr[beg + j] : 0;
            int src = pr >> 3, rel = pr & 7;
            half8 kv = *(const half8*)(kF + (size_t)src * DIM + l16 * 8);
            half8 uv = *(const half8*)(UF +
                                       ((size_t)rel * N_NODES + dst) * DIM +
                                       l16 * 8);
            float s = 0.f;
#pragma unroll
            for (int i = 0; i < 8; ++i) s += (float)kv[i] * (float)uv[i];
            s += __shfl_xor(s, 1, 16);
            s += __shfl_xor(s, 2, 16);
            s += __shfl_xor(s, 4, 16);
            s += __shfl_xor(s, 8, 16);
            float mr = __shfl(m_own, (pr & 7), 8);
            ex = valid ? __expf(s - mr) : 0.f;
        }
        int rel = pr & 7, src = pr >> 3;
        float alpha = ex * __shfl(inv_own, rel, 8);
        half8 v = *(const half8*)(VMF + ((size_t)rel * N_NODES + src) * DIM +
                                  l16 * 8);
#pragma unroll
        for (int i = 0; i < 8; ++i) acc[i] += alpha * (float)v[i];
    }
    // merge acc across the 4 groups (each covers the full 128 dims)
#pragma unroll
    for (int i = 0; i < 8; ++i) {
        acc[i] += __shfl_xor(acc[i], 16, 64);
        acc[i] += __shfl_xor(acc[i], 32, 64);
    }
    if (g == 0) {
        half8 o;
#pragma unroll
        for (int i = 0; i < 8; ++i) o[i] = (_Float16)acc[i];
        *(half8*)(aggF + (size_t)dst * DIM + l16 * 8) = o;
    }
}

// out: 128-node type-uniform chunk MFMA GEMM, fp32 stores with sigmoid gate
__global__ __launch_bounds__(256) void out_kernel(
    const _Float16* __restrict__ aggF, const int* __restrict__ ntype,
    const _Float16* __restrict__ WaT, const float* __restrict__ skip,
    const int* __restrict__ nlist, float* __restrict__ out) {
    __shared__ int nid[128];
    int tid = threadIdx.x;
    if (tid < 128) nid[tid] = nlist[blockIdx.x * 128 + tid];
    __syncthreads();
    if (nid[0] < 0) return;
    int t = ntype[nid[0]];
    float sig = 1.f / (1.f + __expf(-skip[t]));
    int wv = tid >> 6, lane = tid & 63, l16 = lane & 15, quad = lane >> 4;
    int r0 = wv * 32;
    int nA[2];
#pragma unroll
    for (int m = 0; m < 2; ++m) nA[m] = nid[r0 + m * 16 + l16];
    const _Float16* B = WaT + (t << 14);
    f32x4 acc[2][8];
#pragma unroll
    for (int m = 0; m < 2; ++m)
#pragma unroll
        for (int c = 0; c < 8; ++c) acc[m][c] = (f32x4){0.f, 0.f, 0.f, 0.f};
    for (int kk = 0; kk < 4; ++kk) {
        int kb = kk * 32 + quad * 8;
        half8 a[2];
#pragma unroll
        for (int m = 0; m < 2; ++m)
            a[m] = (nA[m] >= 0)
                       ? *(const half8*)(aggF + (size_t)nA[m] * DIM + kb)
                       : (half8){0, 0, 0, 0, 0, 0, 0, 0};
#pragma unroll
        for (int c = 0; c < 8; ++c) {
            half8 b = *(const half8*)(B + (c * 16 + l16) * DIM + kb);
#pragma unroll
            for (int m = 0; m < 2; ++m)
                acc[m][c] = __builtin_amdgcn_mfma_f32_16x16x32_f16(
                    a[m], b, acc[m][c], 0, 0, 0);
        }
    }
#pragma unroll
    for (int m = 0; m < 2; ++m)
#pragma unroll
        for (int c = 0; c < 8; ++c)
#pragma unroll
            for (int rg = 0; rg < 4; ++rg) {
                int node = nid[r0 + m * 16 + quad * 4 + rg];
                if (node >= 0)
                    out[(size_t)node * DIM + c * 16 + l16] =
                        acc[m][c][rg] * sig;
            }
}

extern "C" void kernel_launch(void* const* d_in, const int* in_sizes, int n_in,
                              void* d_out, int out_size, void* d_ws,
                              size_t ws_size, hipStream_t stream) {
    const float* h = (const float*)d_in[0];
    const int* adj = (const int*)d_in[1];
    const int* etype = (const int*)d_in[2];
    const int* ntype = (const int*)d_in[3];
    const float* Wk = (const float*)d_in[6];
    const float* Wq = (const float*)d_in[7];
    const float* Wv = (const float*)d_in[8];
    const float* Wa = (const float*)d_in[9];
    const float* pri = (const float*)d_in[10];
    const float* att = (const float*)d_in[11];
    const float* msg = (const float*)d_in[12];
    const float* skip = (const float*)d_in[13];
    float* out = (float*)d_out;

    int* wsi = (int*)d_ws + OFF_INT;
    _Float16* wsh = (_Float16*)d_ws;
    _Float16* UF = wsh + (size_t)OFF_U * 2;
    _Float16* hF = wsh + (size_t)OFF_HF * 2;
    _Float16* VMF = wsh + (size_t)OFF_VM * 2;
    _Float16* qF = wsh + (size_t)OFF_QF * 2;
    _Float16* kF = wsh + (size_t)OFF_KF * 2;
    _Float16* aggF = wsh + (size_t)OFF_AGGF * 2;
    _Float16* vF = wsh + (size_t)OFF_VF * 2;
    _Float16* attF = wsh + (size_t)OFF_ATTF * 2;
    _Float16* msgT = wsh + (size_t)OFF_MSGT * 2;
    _Float16* WvT = wsh + (size_t)OFF_WVT * 2;
    _Float16* WaT = wsh + (size_t)OFF_WAT * 2;

    init_kernel<<<(100000 + 255) / 256, 256, 0, stream>>>(wsi);
    convert_kernel<<<(RR * DIM * DIM + 255) / 256, 256, 0, stream>>>(
        att, msg, Wv, Wa, attF, msgT, WvT, WaT);
    hconv_kernel<<<(N_NODES * DIM / 4 + 255) / 256, 256, 0, stream>>>(h, hF);
    hist_kernel<<<GRID_E, 256, 0, stream>>>(ntype, adj, wsi);
    offsets_kernel<<<1, 1, 0, stream>>>(wsi);
    scanA_kernel<<<SCAN_BLOCKS, 256, 0, stream>>>(wsi);
    scanB_kernel<<<1, 256, 0, stream>>>(wsi);
    scanC_kernel<<<SCAN_BLOCKS, 256, 0, stream>>>(wsi);
    scatter_kernel<<<GRID_E, 256, 0, stream>>>(ntype, etype, adj, wsi);
    kq_f32_kernel<<<CHUNK_GRID * 2, 256, 0, stream>>>(h, ntype, Wk, Wq,
                                                      wsi + IO_NLIST, kF, qF);
    vproj_kernel<<<CHUNK_GRID, 256, 0, stream>>>(hF, ntype, WvT,
                                                 wsi + IO_NLIST, vF);
    // U pass (reads qF) fully precedes VM pass (writes VMF; qF aliases
    // VMF[7]) — stream ordering guarantees no overlap.
    nr_gemm3_kernel<<<RR * NR3_CHUNKS, 256, 0, stream>>>(qF, attF, UF, pri, 1);
    nr_gemm3_kernel<<<RR * NR3_CHUNKS, 256, 0, stream>>>(vF, msgT, VMF, pri, 0);
    attend_kernel<<<(N_NODES + 3) / 4, 256, 0, stream>>>(
        kF, UF, VMF, wsi + IO_DPR, wsi + IO_DOFF, wsi + IO_DCNT, aggF);
    out_kernel<<<CHUNK_GRID, 256, 0, stream>>>(aggF, ntype, WaT, skip,
                                               wsi + IO_NLIST, out);
}